// Round 1
// baseline (19330.443 us; speedup 1.0000x reference)
//
#include <hip/hip_runtime.h>

// ---------------------------------------------------------------------------
// LSTM_NER_TeacherForcing: B=32, T=512, E=512, H=512, V=50000, C=32, L=2
// Pipeline: embed -> [gemm xw -> persistent scan] x2 layers -> classifier
// Activations/xw stored bf16 (ushort), all accumulation in f32.
// ---------------------------------------------------------------------------

#define BB 32
#define TT 512
#define EE 512
#define HH 512
#define NG 2048   // 4*H gate rows
#define CC 32

__device__ __forceinline__ float bf2f(unsigned short u) {
    return __uint_as_float(((unsigned)u) << 16);
}
__device__ __forceinline__ float bf_lo(unsigned u) { return __uint_as_float(u << 16); }
__device__ __forceinline__ float bf_hi(unsigned u) { return __uint_as_float(u & 0xffff0000u); }
__device__ __forceinline__ unsigned short f2bf(float f) {
    unsigned u = __float_as_uint(f);
    u += 0x7fffu + ((u >> 16) & 1u);   // RNE
    return (unsigned short)(u >> 16);
}

// ---------------------------------------------------------------------------
// 1) Embedding gather: h0[b,t,e] = emb[x[b,t]][e]  (f32 -> bf16)
// grid: (B*T*E/4)/256 = 8192 blocks
__global__ __launch_bounds__(256)
void embed_k(const int* __restrict__ x, const float* __restrict__ emb,
             unsigned short* __restrict__ h0) {
    int idx = blockIdx.x * 256 + threadIdx.x;    // one float4 each
    int row = idx >> 7;                          // E/4 = 128 chunks per row
    int c4  = idx & 127;
    int tok = x[row];
    float4 v = *(const float4*)(emb + ((size_t)tok << 9) + (c4 << 2));
    ushort4 o;
    o.x = f2bf(v.x); o.y = f2bf(v.y); o.z = f2bf(v.z); o.w = f2bf(v.w);
    *(ushort4*)(h0 + ((size_t)row << 9) + (c4 << 2)) = o;
}

// ---------------------------------------------------------------------------
// 2) Input GEMM: C[m,n] = sum_k A[m,k]*Bw[n,k] + bih[n] + bhh[n]
// A: (M,K) bf16, Bw: (2048,K) f32, C: (M,2048) bf16.
// Block: 256 thr, tile 64x64, BK=16, 4x4 micro-tile, k-major LDS.
// grid: (M/64)*(2048/64) = 256*32 = 8192
__global__ __launch_bounds__(256)
void gemm_xw(const unsigned short* __restrict__ A, const float* __restrict__ Bw,
             const float* __restrict__ bih, const float* __restrict__ bhh,
             unsigned short* __restrict__ C, int M, int K) {
    __shared__ float As[16][68];
    __shared__ float Bs[16][68];
    const int bn = blockIdx.x & 31, bm = blockIdx.x >> 5;
    const int tid = threadIdx.x;
    const int tm = tid & 15, tn = tid >> 4;
    const int r = tid >> 2, c4 = tid & 3;
    float acc[4][4] = {};
    for (int k0 = 0; k0 < K; k0 += 16) {
        {
            ushort4 a = *(const ushort4*)(A + (size_t)(bm * 64 + r) * K + k0 + c4 * 4);
            As[c4 * 4 + 0][r] = bf2f(a.x);
            As[c4 * 4 + 1][r] = bf2f(a.y);
            As[c4 * 4 + 2][r] = bf2f(a.z);
            As[c4 * 4 + 3][r] = bf2f(a.w);
            float4 b = *(const float4*)(Bw + (size_t)(bn * 64 + r) * K + k0 + c4 * 4);
            Bs[c4 * 4 + 0][r] = b.x;
            Bs[c4 * 4 + 1][r] = b.y;
            Bs[c4 * 4 + 2][r] = b.z;
            Bs[c4 * 4 + 3][r] = b.w;
        }
        __syncthreads();
#pragma unroll
        for (int kk = 0; kk < 16; ++kk) {
            const float4 a4 = *(const float4*)&As[kk][tm * 4];
            const float4 b4 = *(const float4*)&Bs[kk][tn * 4];
            acc[0][0] = fmaf(a4.x, b4.x, acc[0][0]);
            acc[0][1] = fmaf(a4.x, b4.y, acc[0][1]);
            acc[0][2] = fmaf(a4.x, b4.z, acc[0][2]);
            acc[0][3] = fmaf(a4.x, b4.w, acc[0][3]);
            acc[1][0] = fmaf(a4.y, b4.x, acc[1][0]);
            acc[1][1] = fmaf(a4.y, b4.y, acc[1][1]);
            acc[1][2] = fmaf(a4.y, b4.z, acc[1][2]);
            acc[1][3] = fmaf(a4.y, b4.w, acc[1][3]);
            acc[2][0] = fmaf(a4.z, b4.x, acc[2][0]);
            acc[2][1] = fmaf(a4.z, b4.y, acc[2][1]);
            acc[2][2] = fmaf(a4.z, b4.z, acc[2][2]);
            acc[2][3] = fmaf(a4.z, b4.w, acc[2][3]);
            acc[3][0] = fmaf(a4.w, b4.x, acc[3][0]);
            acc[3][1] = fmaf(a4.w, b4.y, acc[3][1]);
            acc[3][2] = fmaf(a4.w, b4.z, acc[3][2]);
            acc[3][3] = fmaf(a4.w, b4.w, acc[3][3]);
        }
        __syncthreads();
    }
    const int m0 = bm * 64 + tm * 4, n0 = bn * 64 + tn * 4;
    float bsv[4];
#pragma unroll
    for (int j = 0; j < 4; ++j) bsv[j] = bih[n0 + j] + bhh[n0 + j];
#pragma unroll
    for (int i = 0; i < 4; ++i) {
        ushort4 o;
        o.x = f2bf(acc[i][0] + bsv[0]);
        o.y = f2bf(acc[i][1] + bsv[1]);
        o.z = f2bf(acc[i][2] + bsv[2]);
        o.w = f2bf(acc[i][3] + bsv[3]);
        *(ushort4*)(C + (size_t)(m0 + i) * NG + n0) = o;
    }
}

// ---------------------------------------------------------------------------
// 3) Persistent bidirectional LSTM scan for one layer.
// grid = 256 blocks: blk = ((dir*4 + bg)*32 + jb); 256 threads.
// Each block: 8 batch rows (bg), 16 h-columns (jb -> 64 gate rows), all 512 steps.
// Whh slice held in LDS (bf16) for the whole kernel. Group = (dir,bg) = 32 blocks,
// synchronized per step via agent-scope atomic counter; h ping-pong in global bf16.
__global__ __launch_bounds__(256, 1)
void lstm_scan(const float* __restrict__ WhhF, const float* __restrict__ WhhB,
               const unsigned short* __restrict__ xwF, const unsigned short* __restrict__ xwB,
               unsigned short* __restrict__ outcat,   // (B,T,1024) bf16
               unsigned short* __restrict__ h_pp,     // [dir][parity][32][512] bf16
               int* __restrict__ cnt) {               // [8] group counters (pre-zeroed)
    __shared__ unsigned short whhb[64][520];  // 66.5 KB
    __shared__ float hsf[8][520];             // 16.6 KB
    __shared__ float part[4][512];            // 8 KB
    __shared__ float gsh[512];                // 2 KB

    const int blk = blockIdx.x;
    const int jb = blk & 31, grp = blk >> 5, bg = grp & 3, dir = grp >> 2;
    const int tid = threadIdx.x;
    const float* Whh = dir ? WhhB : WhhF;
    const unsigned short* xw = dir ? xwB : xwF;
    const int js = jb << 4;

    // Preload Whh slice: local row r = gate*16 + jj  <->  global row gate*512 + js + jj
    for (int i = tid; i < 64 * 128; i += 256) {
        int r = i >> 7, c4 = i & 127;
        int R = ((r >> 4) << 9) + js + (r & 15);
        float4 v = *(const float4*)(Whh + (size_t)R * HH + c4 * 4);
        ushort4 w;
        w.x = f2bf(v.x); w.y = f2bf(v.y); w.z = f2bf(v.z); w.w = f2bf(v.w);
        *(ushort4*)&whhb[r][c4 * 4] = w;
    }
    float c_st = 0.f;
    const int wv = tid >> 6, lane = tid & 63, bg2 = lane >> 5, ng = lane & 31;
    __syncthreads();

    for (int t = 0; t < TT; ++t) {
        const int tt = dir ? (TT - 1 - t) : t;
        // stage h (bf16 global -> f32 LDS), 8 rows x 512
        {
            const unsigned short* hsrc =
                h_pp + ((size_t)(dir * 2 + (t & 1)) * BB + bg * 8) * HH;
            for (int i = tid; i < 512; i += 256) {   // 8 rows x 64 chunks(8 vals)
                int bl = i >> 6, ch = i & 63;
                uint4 u = *(const uint4*)(hsrc + bl * HH + ch * 8);
                float4 lo = make_float4(bf_lo(u.x), bf_hi(u.x), bf_lo(u.y), bf_hi(u.y));
                float4 hi = make_float4(bf_lo(u.z), bf_hi(u.z), bf_lo(u.w), bf_hi(u.w));
                *(float4*)&hsf[bl][ch * 8] = lo;
                *(float4*)&hsf[bl][ch * 8 + 4] = hi;
            }
        }
        __syncthreads();

        // GEMM: each wave covers k-range [wv*128, wv*128+128), outputs 8b x 64n
        float acc[4][2] = {{0.f,0.f},{0.f,0.f},{0.f,0.f},{0.f,0.f}};
        for (int kc = wv * 16; kc < wv * 16 + 16; ++kc) {   // 8 k per iter
            uint4 w0 = *(const uint4*)&whhb[ng][kc * 8];
            uint4 w1 = *(const uint4*)&whhb[ng + 32][kc * 8];
            float w00 = bf_lo(w0.x), w01 = bf_hi(w0.x), w02 = bf_lo(w0.y), w03 = bf_hi(w0.y);
            float w04 = bf_lo(w0.z), w05 = bf_hi(w0.z), w06 = bf_lo(w0.w), w07 = bf_hi(w0.w);
            float w10 = bf_lo(w1.x), w11 = bf_hi(w1.x), w12 = bf_lo(w1.y), w13 = bf_hi(w1.y);
            float w14 = bf_lo(w1.z), w15 = bf_hi(w1.z), w16 = bf_lo(w1.w), w17 = bf_hi(w1.w);
#pragma unroll
            for (int i = 0; i < 4; ++i) {
                const int bq = bg2 * 4 + i;
                const float4 ha = *(const float4*)&hsf[bq][kc * 8];
                const float4 hb = *(const float4*)&hsf[bq][kc * 8 + 4];
                acc[i][0] = fmaf(ha.x, w00, fmaf(ha.y, w01, fmaf(ha.z, w02, fmaf(ha.w, w03, acc[i][0]))));
                acc[i][0] = fmaf(hb.x, w04, fmaf(hb.y, w05, fmaf(hb.z, w06, fmaf(hb.w, w07, acc[i][0]))));
                acc[i][1] = fmaf(ha.x, w10, fmaf(ha.y, w11, fmaf(ha.z, w12, fmaf(ha.w, w13, acc[i][1]))));
                acc[i][1] = fmaf(hb.x, w14, fmaf(hb.y, w15, fmaf(hb.z, w16, fmaf(hb.w, w17, acc[i][1]))));
            }
        }
#pragma unroll
        for (int i = 0; i < 4; ++i) {
            part[wv][(bg2 * 4 + i) * 64 + ng] = acc[i][0];
            part[wv][(bg2 * 4 + i) * 64 + ng + 32] = acc[i][1];
        }
        __syncthreads();

        // reduce partials + add xw
#pragma unroll
        for (int u = 0; u < 2; ++u) {
            int o = tid + u * 256;
            int bl = o >> 6, rr = o & 63;
            float s = part[0][o] + part[1][o] + part[2][o] + part[3][o];
            int n_glob = ((rr >> 4) << 9) + js + (rr & 15);
            int b_glob = bg * 8 + bl;
            s += bf2f(xw[((size_t)b_glob * TT + tt) * NG + n_glob]);
            gsh[o] = s;
        }
        __syncthreads();

        // gate nonlinearity + state update (threads 0..127: 8b x 16jj)
        if (tid < 128) {
            int bl = tid >> 4, jj = tid & 15;
            float gi = gsh[bl * 64 + jj];
            float gf = gsh[bl * 64 + 16 + jj];
            float gg = gsh[bl * 64 + 32 + jj];
            float go = gsh[bl * 64 + 48 + jj];
            float si = 1.f / (1.f + expf(-gi));
            float sf = 1.f / (1.f + expf(-gf));
            float so = 1.f / (1.f + expf(-go));
            c_st = sf * c_st + si * tanhf(gg);
            float hv = so * tanhf(c_st);
            unsigned short hb16 = f2bf(hv);
            int b_glob = bg * 8 + bl;
            h_pp[((size_t)(dir * 2 + ((t + 1) & 1)) * BB + b_glob) * HH + js + jj] = hb16;
            outcat[((size_t)b_glob * TT + tt) * 1024 + dir * HH + js + jj] = hb16;
        }
        __syncthreads();

        // group barrier: 32 blocks of (dir,bg)
        if (tid == 0) {
            __hip_atomic_fetch_add(&cnt[grp], 1, __ATOMIC_RELEASE, __HIP_MEMORY_SCOPE_AGENT);
            const int target = 32 * (t + 1);
            while (__hip_atomic_load(&cnt[grp], __ATOMIC_ACQUIRE, __HIP_MEMORY_SCOPE_AGENT) < target) {
                __builtin_amdgcn_s_sleep(2);
            }
        }
        __syncthreads();
    }
}

// ---------------------------------------------------------------------------
// 4) Classifier + log_softmax, transposed write (B,C,T).
// Block: 256 thr = 8 (b,t) x 32 classes; grid 2048.
__global__ __launch_bounds__(256)
void classifier_k(const unsigned short* __restrict__ hcat, const float* __restrict__ truth,
                  const int* __restrict__ tf, const float* __restrict__ Wc,
                  const float* __restrict__ bc, float* __restrict__ out) {
    __shared__ float feat[8][1024];
    __shared__ float featp[8];
    const int tid = threadIdx.x;
    const int bt0 = blockIdx.x * 8;
    for (int i = tid; i < 8 * 128; i += 256) {   // 8 rows x 128 chunks(8 vals)
        int bl = i >> 7, ch = i & 127;
        uint4 u = *(const uint4*)(hcat + (size_t)(bt0 + bl) * 1024 + ch * 8);
        *(float4*)&feat[bl][ch * 8] = make_float4(bf_lo(u.x), bf_hi(u.x), bf_lo(u.y), bf_hi(u.y));
        *(float4*)&feat[bl][ch * 8 + 4] = make_float4(bf_lo(u.z), bf_hi(u.z), bf_lo(u.w), bf_hi(u.w));
    }
    if (tid < 8) {
        int bt = bt0 + tid;
        int t = bt & 511;
        featp[tid] = (t > 0 && tf[0] != 0) ? truth[bt - 1] : 0.f;
    }
    __syncthreads();
    const int bl = tid >> 5, c = tid & 31;
    const int bt = bt0 + bl;
    float acc = featp[bl] * Wc[c * 1025] + bc[c];
    const float* w = Wc + c * 1025 + 1;
    for (int f4 = 0; f4 < 256; ++f4) {
        const float4 fv = *(const float4*)&feat[bl][f4 * 4];
        acc = fmaf(fv.x, w[f4 * 4 + 0],
              fmaf(fv.y, w[f4 * 4 + 1],
              fmaf(fv.z, w[f4 * 4 + 2],
              fmaf(fv.w, w[f4 * 4 + 3], acc))));
    }
    float m = acc;
#pragma unroll
    for (int mk = 16; mk; mk >>= 1) m = fmaxf(m, __shfl_xor(m, mk));
    float e = expf(acc - m);
    float s = e;
#pragma unroll
    for (int mk = 16; mk; mk >>= 1) s += __shfl_xor(s, mk);
    float lse = m + logf(s);
    int b = bt >> 9, t = bt & 511;
    out[((size_t)b * CC + c) * TT + t] = acc - lse;
}

// ---------------------------------------------------------------------------
extern "C" void kernel_launch(void* const* d_in, const int* in_sizes, int n_in,
                              void* d_out, int out_size, void* d_ws, size_t ws_size,
                              hipStream_t stream) {
    const int* x = (const int*)d_in[0];
    const float* truth = (const float*)d_in[1];
    const int* tf = (const int*)d_in[2];
    const float* emb = (const float*)d_in[3];
    const float* Wih0f = (const float*)d_in[4];
    const float* Whh0f = (const float*)d_in[5];
    const float* bih0f = (const float*)d_in[6];
    const float* bhh0f = (const float*)d_in[7];
    const float* Wih0b = (const float*)d_in[8];
    const float* Whh0b = (const float*)d_in[9];
    const float* bih0b = (const float*)d_in[10];
    const float* bhh0b = (const float*)d_in[11];
    const float* Wih1f = (const float*)d_in[12];
    const float* Whh1f = (const float*)d_in[13];
    const float* bih1f = (const float*)d_in[14];
    const float* bhh1f = (const float*)d_in[15];
    const float* Wih1b = (const float*)d_in[16];
    const float* Whh1b = (const float*)d_in[17];
    const float* bih1b = (const float*)d_in[18];
    const float* bhh1b = (const float*)d_in[19];
    const float* Wc = (const float*)d_in[20];
    const float* bc = (const float*)d_in[21];
    float* out = (float*)d_out;

    // ws layout (bytes)
    const size_t off_h0  = 0;                       // (B,T,512) bf16 : 16 MB
    const size_t off_xwf = 16777216;                // (B,T,2048) bf16: 64 MB
    const size_t off_xwb = off_xwf + 67108864;
    const size_t off_hc1 = off_xwb + 67108864;      // (B,T,1024) bf16: 32 MB
    const size_t off_hc2 = off_hc1 + 33554432;
    const size_t off_hpp = off_hc2 + 33554432;      // 128 KB
    const size_t off_cnt = off_hpp + 131072;
    const size_t need = off_cnt + 128;
    if (ws_size < need) return;

    char* ws = (char*)d_ws;
    unsigned short* h0  = (unsigned short*)(ws + off_h0);
    unsigned short* xwf = (unsigned short*)(ws + off_xwf);
    unsigned short* xwb = (unsigned short*)(ws + off_xwb);
    unsigned short* hc1 = (unsigned short*)(ws + off_hc1);
    unsigned short* hc2 = (unsigned short*)(ws + off_hc2);
    unsigned short* hpp = (unsigned short*)(ws + off_hpp);
    int* cnt = (int*)(ws + off_cnt);

    embed_k<<<8192, 256, 0, stream>>>(x, emb, h0);

    // layer 0
    gemm_xw<<<8192, 256, 0, stream>>>(h0, Wih0f, bih0f, bhh0f, xwf, BB * TT, EE);
    gemm_xw<<<8192, 256, 0, stream>>>(h0, Wih0b, bih0b, bhh0b, xwb, BB * TT, EE);
    (void)hipMemsetAsync(ws + off_hpp, 0, 131072 + 128, stream);
    lstm_scan<<<256, 256, 0, stream>>>(Whh0f, Whh0b, xwf, xwb, hc1, hpp, cnt);

    // layer 1
    gemm_xw<<<8192, 256, 0, stream>>>(hc1, Wih1f, bih1f, bhh1f, xwf, BB * TT, 1024);
    gemm_xw<<<8192, 256, 0, stream>>>(hc1, Wih1b, bih1b, bhh1b, xwb, BB * TT, 1024);
    (void)hipMemsetAsync(ws + off_hpp, 0, 131072 + 128, stream);
    lstm_scan<<<256, 256, 0, stream>>>(Whh1f, Whh1b, xwf, xwb, hc2, hpp, cnt);

    classifier_k<<<2048, 256, 0, stream>>>(hc2, truth, tf, Wc, bc, out);
}

// Round 2
// 16346.803 us; speedup vs baseline: 1.1825x; 1.1825x over previous
//
#include <hip/hip_runtime.h>

// ---------------------------------------------------------------------------
// LSTM_NER_TeacherForcing: B=32, T=512, E=512, H=512, V=50000, C=32, L=2
// embed -> [mfma gemm xw -> persistent scan] x2 -> classifier
// Round 2: (a) scan barrier: relaxed polls + single acquire fence per step,
//          xw prefetch hoisted under GEMM compute;
//          (b) input GEMMs moved to bf16 MFMA (16x16x32).
// ---------------------------------------------------------------------------

#define BB 32
#define TT 512
#define EE 512
#define HH 512
#define NG 2048   // 4*H gate rows
#define CC 32

typedef __attribute__((ext_vector_type(8))) short short8v;
typedef __attribute__((ext_vector_type(4))) float float4v;

__device__ __forceinline__ float bf2f(unsigned short u) {
    return __uint_as_float(((unsigned)u) << 16);
}
__device__ __forceinline__ float bf_lo(unsigned u) { return __uint_as_float(u << 16); }
__device__ __forceinline__ float bf_hi(unsigned u) { return __uint_as_float(u & 0xffff0000u); }
__device__ __forceinline__ unsigned short f2bf(float f) {
    unsigned u = __float_as_uint(f);
    u += 0x7fffu + ((u >> 16) & 1u);   // RNE
    return (unsigned short)(u >> 16);
}

// ---------------------------------------------------------------------------
// 1) Embedding gather: h0[b,t,e] = emb[x[b,t]][e]  (f32 -> bf16)
__global__ __launch_bounds__(256)
void embed_k(const int* __restrict__ x, const float* __restrict__ emb,
             unsigned short* __restrict__ h0) {
    int idx = blockIdx.x * 256 + threadIdx.x;    // one float4 each
    int row = idx >> 7;                          // E/4 = 128 chunks per row
    int c4  = idx & 127;
    int tok = x[row];
    float4 v = *(const float4*)(emb + ((size_t)tok << 9) + (c4 << 2));
    ushort4 o;
    o.x = f2bf(v.x); o.y = f2bf(v.y); o.z = f2bf(v.z); o.w = f2bf(v.w);
    *(ushort4*)(h0 + ((size_t)row << 9) + (c4 << 2)) = o;
}

// ---------------------------------------------------------------------------
// 2) Input GEMM via MFMA: C[m,n] = sum_k A[m,k]*Bw[n,k] + bih[n] + bhh[n]
// A: (M,K) bf16, Bw: (2048,K) f32 (converted to bf16 in staging), C bf16.
// Block 256 thr = 4 waves; tile 64x64; BK=32; wave quadrants 32x32 (2x2 frags).
// grid: (M/64)*32
__global__ __launch_bounds__(256)
void gemm_xw(const unsigned short* __restrict__ A, const float* __restrict__ Bw,
             const float* __restrict__ bih, const float* __restrict__ bhh,
             unsigned short* __restrict__ C, int M, int K) {
    __shared__ unsigned short As[64][40];   // row-major (m,k), pad to 40
    __shared__ unsigned short Bs[64][40];   // (n,k)
    const int bn = blockIdx.x & 31, bm = blockIdx.x >> 5;
    const int tid = threadIdx.x;
    const int wv = tid >> 6, lane = tid & 63;
    const int wm = (wv >> 1) * 32, wn = (wv & 1) * 32;
    const int sr = tid >> 2, sk = (tid & 3) * 8;   // staging: row, k-chunk of 8
    const int fr = lane & 15, fk = (lane >> 4) * 8;

    float4v acc[2][2];
#pragma unroll
    for (int i = 0; i < 2; ++i)
#pragma unroll
        for (int j = 0; j < 2; ++j) acc[i][j] = (float4v)(0.0f);

    for (int k0 = 0; k0 < K; k0 += 32) {
        // stage A (bf16 copy, 16B/thread)
        *(uint4*)&As[sr][sk] = *(const uint4*)(A + (size_t)(bm * 64 + sr) * K + k0 + sk);
        // stage B (f32 -> bf16)
        const float* bp = Bw + (size_t)(bn * 64 + sr) * K + k0 + sk;
        const float4 b0 = *(const float4*)bp;
        const float4 b1 = *(const float4*)(bp + 4);
        ushort4 o0 = {f2bf(b0.x), f2bf(b0.y), f2bf(b0.z), f2bf(b0.w)};
        ushort4 o1 = {f2bf(b1.x), f2bf(b1.y), f2bf(b1.z), f2bf(b1.w)};
        *(ushort4*)&Bs[sr][sk] = o0;
        *(ushort4*)&Bs[sr][sk + 4] = o1;
        __syncthreads();

        short8v a0 = *(const short8v*)&As[wm + fr][fk];
        short8v a1 = *(const short8v*)&As[wm + 16 + fr][fk];
        short8v bb0 = *(const short8v*)&Bs[wn + fr][fk];
        short8v bb1 = *(const short8v*)&Bs[wn + 16 + fr][fk];
        acc[0][0] = __builtin_amdgcn_mfma_f32_16x16x32_bf16(a0, bb0, acc[0][0], 0, 0, 0);
        acc[0][1] = __builtin_amdgcn_mfma_f32_16x16x32_bf16(a0, bb1, acc[0][1], 0, 0, 0);
        acc[1][0] = __builtin_amdgcn_mfma_f32_16x16x32_bf16(a1, bb0, acc[1][0], 0, 0, 0);
        acc[1][1] = __builtin_amdgcn_mfma_f32_16x16x32_bf16(a1, bb1, acc[1][1], 0, 0, 0);
        __syncthreads();
    }

    const int r4 = (lane >> 4) * 4;
#pragma unroll
    for (int nt = 0; nt < 2; ++nt) {
        const int nglob = bn * 64 + wn + nt * 16 + fr;
        const float bias = bih[nglob] + bhh[nglob];
#pragma unroll
        for (int mt = 0; mt < 2; ++mt) {
#pragma unroll
            for (int i = 0; i < 4; ++i) {
                const int mglob = bm * 64 + wm + mt * 16 + r4 + i;
                C[(size_t)mglob * NG + nglob] = f2bf(acc[mt][nt][i] + bias);
            }
        }
    }
}

// ---------------------------------------------------------------------------
// 3) Persistent bidirectional LSTM scan for one layer.
// grid = 256 blocks: blk = ((dir*4 + bg)*32 + jb); 256 threads.
// Whh slice in LDS (bf16); group = (dir,bg) = 32 blocks; h ping-pong global.
// Sync: release fetch_add + RELAXED polls + one acquire fence per step.
__global__ __launch_bounds__(256, 1)
void lstm_scan(const float* __restrict__ WhhF, const float* __restrict__ WhhB,
               const unsigned short* __restrict__ xwF, const unsigned short* __restrict__ xwB,
               unsigned short* __restrict__ outcat,   // (B,T,1024) bf16
               unsigned short* __restrict__ h_pp,     // [dir][parity][32][512] bf16
               int* __restrict__ cnt) {               // [8] group counters (pre-zeroed)
    __shared__ unsigned short whhb[64][520];  // 66.5 KB
    __shared__ float hsf[8][520];             // 16.6 KB
    __shared__ float part[4][512];            // 8 KB
    __shared__ float gsh[512];                // 2 KB

    const int blk = blockIdx.x;
    const int jb = blk & 31, grp = blk >> 5, bg = grp & 3, dir = grp >> 2;
    const int tid = threadIdx.x;
    const float* Whh = dir ? WhhB : WhhF;
    const unsigned short* xw = dir ? xwB : xwF;
    const int js = jb << 4;

    // Preload Whh slice: local row r = gate*16 + jj  <->  global row gate*512 + js + jj
    for (int i = tid; i < 64 * 128; i += 256) {
        int r = i >> 7, c4 = i & 127;
        int R = ((r >> 4) << 9) + js + (r & 15);
        float4 v = *(const float4*)(Whh + (size_t)R * HH + c4 * 4);
        ushort4 w;
        w.x = f2bf(v.x); w.y = f2bf(v.y); w.z = f2bf(v.z); w.w = f2bf(v.w);
        *(ushort4*)&whhb[r][c4 * 4] = w;
    }
    float c_st = 0.f;
    const int wv = tid >> 6, lane = tid & 63, bg2 = lane >> 5, ng = lane & 31;
    // precomputed reduce-phase coordinates (t-independent)
    int nglob_u[2], bglob_u[2];
#pragma unroll
    for (int u = 0; u < 2; ++u) {
        int o = tid + u * 256;
        int bl = o >> 6, rr = o & 63;
        nglob_u[u] = ((rr >> 4) << 9) + js + (rr & 15);
        bglob_u[u] = bg * 8 + bl;
    }
    __syncthreads();

    for (int t = 0; t < TT; ++t) {
        const int tt = dir ? (TT - 1 - t) : t;
        // stage h (bf16 global -> f32 LDS), 8 rows x 512
        {
            const unsigned short* hsrc =
                h_pp + ((size_t)(dir * 2 + (t & 1)) * BB + bg * 8) * HH;
            for (int i = tid; i < 512; i += 256) {   // 8 rows x 64 chunks(8 vals)
                int bl = i >> 6, ch = i & 63;
                uint4 u = *(const uint4*)(hsrc + bl * HH + ch * 8);
                float4 lo = make_float4(bf_lo(u.x), bf_hi(u.x), bf_lo(u.y), bf_hi(u.y));
                float4 hi = make_float4(bf_lo(u.z), bf_hi(u.z), bf_lo(u.w), bf_hi(u.w));
                *(float4*)&hsf[bl][ch * 8] = lo;
                *(float4*)&hsf[bl][ch * 8 + 4] = hi;
            }
        }
        __syncthreads();

        // prefetch xw gate biases for this step; latency hides under the GEMM
        float xv0 = bf2f(xw[((size_t)bglob_u[0] * TT + tt) * NG + nglob_u[0]]);
        float xv1 = bf2f(xw[((size_t)bglob_u[1] * TT + tt) * NG + nglob_u[1]]);

        // GEMM: each wave covers k-range [wv*128, wv*128+128), outputs 8b x 64n
        float acc[4][2] = {{0.f,0.f},{0.f,0.f},{0.f,0.f},{0.f,0.f}};
        for (int kc = wv * 16; kc < wv * 16 + 16; ++kc) {   // 8 k per iter
            uint4 w0 = *(const uint4*)&whhb[ng][kc * 8];
            uint4 w1 = *(const uint4*)&whhb[ng + 32][kc * 8];
            float w00 = bf_lo(w0.x), w01 = bf_hi(w0.x), w02 = bf_lo(w0.y), w03 = bf_hi(w0.y);
            float w04 = bf_lo(w0.z), w05 = bf_hi(w0.z), w06 = bf_lo(w0.w), w07 = bf_hi(w0.w);
            float w10 = bf_lo(w1.x), w11 = bf_hi(w1.x), w12 = bf_lo(w1.y), w13 = bf_hi(w1.y);
            float w14 = bf_lo(w1.z), w15 = bf_hi(w1.z), w16 = bf_lo(w1.w), w17 = bf_hi(w1.w);
#pragma unroll
            for (int i = 0; i < 4; ++i) {
                const int bq = bg2 * 4 + i;
                const float4 ha = *(const float4*)&hsf[bq][kc * 8];
                const float4 hb = *(const float4*)&hsf[bq][kc * 8 + 4];
                acc[i][0] = fmaf(ha.x, w00, fmaf(ha.y, w01, fmaf(ha.z, w02, fmaf(ha.w, w03, acc[i][0]))));
                acc[i][0] = fmaf(hb.x, w04, fmaf(hb.y, w05, fmaf(hb.z, w06, fmaf(hb.w, w07, acc[i][0]))));
                acc[i][1] = fmaf(ha.x, w10, fmaf(ha.y, w11, fmaf(ha.z, w12, fmaf(ha.w, w13, acc[i][1]))));
                acc[i][1] = fmaf(hb.x, w14, fmaf(hb.y, w15, fmaf(hb.z, w16, fmaf(hb.w, w17, acc[i][1]))));
            }
        }
#pragma unroll
        for (int i = 0; i < 4; ++i) {
            part[wv][(bg2 * 4 + i) * 64 + ng] = acc[i][0];
            part[wv][(bg2 * 4 + i) * 64 + ng + 32] = acc[i][1];
        }
        __syncthreads();

        // reduce partials + add prefetched xw
        {
            int o0 = tid;
            gsh[o0] = part[0][o0] + part[1][o0] + part[2][o0] + part[3][o0] + xv0;
            int o1 = tid + 256;
            gsh[o1] = part[0][o1] + part[1][o1] + part[2][o1] + part[3][o1] + xv1;
        }
        __syncthreads();

        // gate nonlinearity + state update (threads 0..127: 8b x 16jj)
        if (tid < 128) {
            int bl = tid >> 4, jj = tid & 15;
            float gi = gsh[bl * 64 + jj];
            float gf = gsh[bl * 64 + 16 + jj];
            float gg = gsh[bl * 64 + 32 + jj];
            float go = gsh[bl * 64 + 48 + jj];
            float si = 1.f / (1.f + expf(-gi));
            float sf = 1.f / (1.f + expf(-gf));
            float so = 1.f / (1.f + expf(-go));
            c_st = sf * c_st + si * tanhf(gg);
            float hv = so * tanhf(c_st);
            unsigned short hb16 = f2bf(hv);
            int b_glob = bg * 8 + bl;
            h_pp[((size_t)(dir * 2 + ((t + 1) & 1)) * BB + b_glob) * HH + js + jj] = hb16;
            outcat[((size_t)b_glob * TT + tt) * 1024 + dir * HH + js + jj] = hb16;
        }
        __syncthreads();

        // group barrier: release add, RELAXED polls, single acquire fence
        if (tid == 0) {
            __hip_atomic_fetch_add(&cnt[grp], 1, __ATOMIC_RELEASE, __HIP_MEMORY_SCOPE_AGENT);
            const int target = 32 * (t + 1);
            while (__hip_atomic_load(&cnt[grp], __ATOMIC_RELAXED, __HIP_MEMORY_SCOPE_AGENT) < target) {
                __builtin_amdgcn_s_sleep(1);
            }
            __builtin_amdgcn_fence(__ATOMIC_ACQUIRE, "agent");
        }
        __syncthreads();
    }
}

// ---------------------------------------------------------------------------
// 4) Classifier + log_softmax, transposed write (B,C,T).
__global__ __launch_bounds__(256)
void classifier_k(const unsigned short* __restrict__ hcat, const float* __restrict__ truth,
                  const int* __restrict__ tf, const float* __restrict__ Wc,
                  const float* __restrict__ bc, float* __restrict__ out) {
    __shared__ float feat[8][1024];
    __shared__ float featp[8];
    const int tid = threadIdx.x;
    const int bt0 = blockIdx.x * 8;
    for (int i = tid; i < 8 * 128; i += 256) {   // 8 rows x 128 chunks(8 vals)
        int bl = i >> 7, ch = i & 127;
        uint4 u = *(const uint4*)(hcat + (size_t)(bt0 + bl) * 1024 + ch * 8);
        *(float4*)&feat[bl][ch * 8] = make_float4(bf_lo(u.x), bf_hi(u.x), bf_lo(u.y), bf_hi(u.y));
        *(float4*)&feat[bl][ch * 8 + 4] = make_float4(bf_lo(u.z), bf_hi(u.z), bf_lo(u.w), bf_hi(u.w));
    }
    if (tid < 8) {
        int bt = bt0 + tid;
        int t = bt & 511;
        featp[tid] = (t > 0 && tf[0] != 0) ? truth[bt - 1] : 0.f;
    }
    __syncthreads();
    const int bl = tid >> 5, c = tid & 31;
    const int bt = bt0 + bl;
    float acc = featp[bl] * Wc[c * 1025] + bc[c];
    const float* w = Wc + c * 1025 + 1;
    for (int f4 = 0; f4 < 256; ++f4) {
        const float4 fv = *(const float4*)&feat[bl][f4 * 4];
        acc = fmaf(fv.x, w[f4 * 4 + 0],
              fmaf(fv.y, w[f4 * 4 + 1],
              fmaf(fv.z, w[f4 * 4 + 2],
              fmaf(fv.w, w[f4 * 4 + 3], acc))));
    }
    float m = acc;
#pragma unroll
    for (int mk = 16; mk; mk >>= 1) m = fmaxf(m, __shfl_xor(m, mk));
    float e = expf(acc - m);
    float s = e;
#pragma unroll
    for (int mk = 16; mk; mk >>= 1) s += __shfl_xor(s, mk);
    float lse = m + logf(s);
    int b = bt >> 9, t = bt & 511;
    out[((size_t)b * CC + c) * TT + t] = acc - lse;
}

// ---------------------------------------------------------------------------
extern "C" void kernel_launch(void* const* d_in, const int* in_sizes, int n_in,
                              void* d_out, int out_size, void* d_ws, size_t ws_size,
                              hipStream_t stream) {
    const int* x = (const int*)d_in[0];
    const float* truth = (const float*)d_in[1];
    const int* tf = (const int*)d_in[2];
    const float* emb = (const float*)d_in[3];
    const float* Wih0f = (const float*)d_in[4];
    const float* Whh0f = (const float*)d_in[5];
    const float* bih0f = (const float*)d_in[6];
    const float* bhh0f = (const float*)d_in[7];
    const float* Wih0b = (const float*)d_in[8];
    const float* Whh0b = (const float*)d_in[9];
    const float* bih0b = (const float*)d_in[10];
    const float* bhh0b = (const float*)d_in[11];
    const float* Wih1f = (const float*)d_in[12];
    const float* Whh1f = (const float*)d_in[13];
    const float* bih1f = (const float*)d_in[14];
    const float* bhh1f = (const float*)d_in[15];
    const float* Wih1b = (const float*)d_in[16];
    const float* Whh1b = (const float*)d_in[17];
    const float* bih1b = (const float*)d_in[18];
    const float* bhh1b = (const float*)d_in[19];
    const float* Wc = (const float*)d_in[20];
    const float* bc = (const float*)d_in[21];
    float* out = (float*)d_out;

    // ws layout (bytes)
    const size_t off_h0  = 0;                       // (B,T,512) bf16 : 16 MB
    const size_t off_xwf = 16777216;                // (B,T,2048) bf16: 64 MB
    const size_t off_xwb = off_xwf + 67108864;
    const size_t off_hc1 = off_xwb + 67108864;      // (B,T,1024) bf16: 32 MB
    const size_t off_hc2 = off_hc1 + 33554432;
    const size_t off_hpp = off_hc2 + 33554432;      // 128 KB
    const size_t off_cnt = off_hpp + 131072;
    const size_t need = off_cnt + 128;
    if (ws_size < need) return;

    char* ws = (char*)d_ws;
    unsigned short* h0  = (unsigned short*)(ws + off_h0);
    unsigned short* xwf = (unsigned short*)(ws + off_xwf);
    unsigned short* xwb = (unsigned short*)(ws + off_xwb);
    unsigned short* hc1 = (unsigned short*)(ws + off_hc1);
    unsigned short* hc2 = (unsigned short*)(ws + off_hc2);
    unsigned short* hpp = (unsigned short*)(ws + off_hpp);
    int* cnt = (int*)(ws + off_cnt);

    embed_k<<<8192, 256, 0, stream>>>(x, emb, h0);

    // layer 0
    gemm_xw<<<8192, 256, 0, stream>>>(h0, Wih0f, bih0f, bhh0f, xwf, BB * TT, EE);
    gemm_xw<<<8192, 256, 0, stream>>>(h0, Wih0b, bih0b, bhh0b, xwb, BB * TT, EE);
    (void)hipMemsetAsync(ws + off_hpp, 0, 131072 + 128, stream);
    lstm_scan<<<256, 256, 0, stream>>>(Whh0f, Whh0b, xwf, xwb, hc1, hpp, cnt);

    // layer 1
    gemm_xw<<<8192, 256, 0, stream>>>(hc1, Wih1f, bih1f, bhh1f, xwf, BB * TT, 1024);
    gemm_xw<<<8192, 256, 0, stream>>>(hc1, Wih1b, bih1b, bhh1b, xwb, BB * TT, 1024);
    (void)hipMemsetAsync(ws + off_hpp, 0, 131072 + 128, stream);
    lstm_scan<<<256, 256, 0, stream>>>(Whh1f, Whh1b, xwf, xwb, hc2, hpp, cnt);

    classifier_k<<<2048, 256, 0, stream>>>(hc2, truth, tf, Wc, bc, out);
}

// Round 3
// 13041.202 us; speedup vs baseline: 1.4823x; 1.2535x over previous
//
#include <hip/hip_runtime.h>

// ---------------------------------------------------------------------------
// LSTM_NER_TeacherForcing: B=32, T=512, E=512, H=512, V=50000, C=32, L=2
// embed -> [mfma gemm xw -> persistent scan] x2 -> classifier
// Round 3: (a) per-group barrier counters padded to 1KB (was: all 8 on one
//          cache line -> 256 same-line RMWs/step); (b) grp = blk&7 so each
//          group's 32 blocks land on one XCD (round-robin dispatch);
//          (c) xw stored permuted [jb][t][b][64] -> scan reads 1KB contiguous.
// ---------------------------------------------------------------------------

#define BB 32
#define TT 512
#define EE 512
#define HH 512
#define NG 2048   // 4*H gate rows
#define CC 32

typedef __attribute__((ext_vector_type(8))) short short8v;
typedef __attribute__((ext_vector_type(4))) float float4v;

__device__ __forceinline__ float bf2f(unsigned short u) {
    return __uint_as_float(((unsigned)u) << 16);
}
__device__ __forceinline__ float bf_lo(unsigned u) { return __uint_as_float(u << 16); }
__device__ __forceinline__ float bf_hi(unsigned u) { return __uint_as_float(u & 0xffff0000u); }
__device__ __forceinline__ unsigned short f2bf(float f) {
    unsigned u = __float_as_uint(f);
    u += 0x7fffu + ((u >> 16) & 1u);   // RNE
    return (unsigned short)(u >> 16);
}

// ---------------------------------------------------------------------------
// 1) Embedding gather: h0[b,t,e] = emb[x[b,t]][e]  (f32 -> bf16)
__global__ __launch_bounds__(256)
void embed_k(const int* __restrict__ x, const float* __restrict__ emb,
             unsigned short* __restrict__ h0) {
    int idx = blockIdx.x * 256 + threadIdx.x;    // one float4 each
    int row = idx >> 7;                          // E/4 = 128 chunks per row
    int c4  = idx & 127;
    int tok = x[row];
    float4 v = *(const float4*)(emb + ((size_t)tok << 9) + (c4 << 2));
    ushort4 o;
    o.x = f2bf(v.x); o.y = f2bf(v.y); o.z = f2bf(v.z); o.w = f2bf(v.w);
    *(ushort4*)(h0 + ((size_t)row << 9) + (c4 << 2)) = o;
}

// ---------------------------------------------------------------------------
// 2) Input GEMM via MFMA, output written PERMUTED for the scan:
// xwp[((jb*512 + t)*32 + b)*64 + gate*16 + jj], jb=(n&511)>>4, gate=n>>9, jj=n&15
// A: (M=B*T, K) bf16 rows m=b*512+t; Bw: (2048,K) f32 -> bf16 staged.
// Block 256 thr = 4 waves; tile 64x64; BK=32; wave quadrants 32x32 (2x2 frags).
__global__ __launch_bounds__(256)
void gemm_xw(const unsigned short* __restrict__ A, const float* __restrict__ Bw,
             const float* __restrict__ bih, const float* __restrict__ bhh,
             unsigned short* __restrict__ Cp, int M, int K) {
    __shared__ unsigned short As[64][40];   // row-major (m,k), pad to 40
    __shared__ unsigned short Bs[64][40];   // (n,k)
    const int bn = blockIdx.x & 31, bm = blockIdx.x >> 5;
    const int tid = threadIdx.x;
    const int wv = tid >> 6, lane = tid & 63;
    const int wm = (wv >> 1) * 32, wn = (wv & 1) * 32;
    const int sr = tid >> 2, sk = (tid & 3) * 8;   // staging: row, k-chunk of 8
    const int fr = lane & 15, fk = (lane >> 4) * 8;

    float4v acc[2][2];
#pragma unroll
    for (int i = 0; i < 2; ++i)
#pragma unroll
        for (int j = 0; j < 2; ++j) acc[i][j] = (float4v)(0.0f);

    for (int k0 = 0; k0 < K; k0 += 32) {
        // stage A (bf16 copy, 16B/thread)
        *(uint4*)&As[sr][sk] = *(const uint4*)(A + (size_t)(bm * 64 + sr) * K + k0 + sk);
        // stage B (f32 -> bf16)
        const float* bp = Bw + (size_t)(bn * 64 + sr) * K + k0 + sk;
        const float4 b0 = *(const float4*)bp;
        const float4 b1 = *(const float4*)(bp + 4);
        ushort4 o0 = {f2bf(b0.x), f2bf(b0.y), f2bf(b0.z), f2bf(b0.w)};
        ushort4 o1 = {f2bf(b1.x), f2bf(b1.y), f2bf(b1.z), f2bf(b1.w)};
        *(ushort4*)&Bs[sr][sk] = o0;
        *(ushort4*)&Bs[sr][sk + 4] = o1;
        __syncthreads();

        short8v a0 = *(const short8v*)&As[wm + fr][fk];
        short8v a1 = *(const short8v*)&As[wm + 16 + fr][fk];
        short8v bb0 = *(const short8v*)&Bs[wn + fr][fk];
        short8v bb1 = *(const short8v*)&Bs[wn + 16 + fr][fk];
        acc[0][0] = __builtin_amdgcn_mfma_f32_16x16x32_bf16(a0, bb0, acc[0][0], 0, 0, 0);
        acc[0][1] = __builtin_amdgcn_mfma_f32_16x16x32_bf16(a0, bb1, acc[0][1], 0, 0, 0);
        acc[1][0] = __builtin_amdgcn_mfma_f32_16x16x32_bf16(a1, bb0, acc[1][0], 0, 0, 0);
        acc[1][1] = __builtin_amdgcn_mfma_f32_16x16x32_bf16(a1, bb1, acc[1][1], 0, 0, 0);
        __syncthreads();
    }

    const int r4 = (lane >> 4) * 4;
#pragma unroll
    for (int nt = 0; nt < 2; ++nt) {
        const int nglob = bn * 64 + wn + nt * 16 + fr;
        const float bias = bih[nglob] + bhh[nglob];
        const int gate = nglob >> 9;
        const int jbv = (nglob & 511) >> 4;
        const int loc = gate * 16 + (nglob & 15);
#pragma unroll
        for (int mt = 0; mt < 2; ++mt) {
#pragma unroll
            for (int i = 0; i < 4; ++i) {
                const int mglob = bm * 64 + wm + mt * 16 + r4 + i;
                const int b = mglob >> 9, t = mglob & 511;
                Cp[(((size_t)jbv * 512 + t) * 32 + b) * 64 + loc] =
                    f2bf(acc[mt][nt][i] + bias);
            }
        }
    }
}

// ---------------------------------------------------------------------------
// 3) Persistent bidirectional LSTM scan for one layer.
// grid = 256 blocks: grp = blk&7 (same-XCD group under round-robin dispatch),
// jb = blk>>3. grp = dir*4+bg: 8 batch rows, 16 h-cols (64 gate rows), 512 steps.
// Whh slice in LDS (bf16); h ping-pong in global bf16.
// Barrier: release fetch_add on 1KB-padded counter + relaxed polls + acquire.
__global__ __launch_bounds__(256, 1)
void lstm_scan(const float* __restrict__ WhhF, const float* __restrict__ WhhB,
               const unsigned short* __restrict__ xwF, const unsigned short* __restrict__ xwB,
               unsigned short* __restrict__ outcat,   // (B,T,1024) bf16
               unsigned short* __restrict__ h_pp,     // [dir][parity][32][512] bf16
               int* __restrict__ cnt) {               // 8 counters, 1KB apart
    __shared__ unsigned short whhb[64][520];  // 66.5 KB
    __shared__ float hsf[8][520];             // 16.6 KB
    __shared__ float part[4][512];            // 8 KB
    __shared__ float gsh[512];                // 2 KB

    const int blk = blockIdx.x;
    const int grp = blk & 7, jb = blk >> 3;
    const int bg = grp & 3, dir = grp >> 2;
    const int tid = threadIdx.x;
    const float* Whh = dir ? WhhB : WhhF;
    const unsigned short* xw = dir ? xwB : xwF;
    const int js = jb << 4;
    int* const mycnt = cnt + (grp << 8);

    // Preload Whh slice: local row r = gate*16 + jj  <->  global row gate*512 + js + jj
    for (int i = tid; i < 64 * 128; i += 256) {
        int r = i >> 7, c4 = i & 127;
        int R = ((r >> 4) << 9) + js + (r & 15);
        float4 v = *(const float4*)(Whh + (size_t)R * HH + c4 * 4);
        ushort4 w;
        w.x = f2bf(v.x); w.y = f2bf(v.y); w.z = f2bf(v.z); w.w = f2bf(v.w);
        *(ushort4*)&whhb[r][c4 * 4] = w;
    }
    float c_st = 0.f;
    const int wv = tid >> 6, lane = tid & 63, bg2 = lane >> 5, ng = lane & 31;
    __syncthreads();

    for (int t = 0; t < TT; ++t) {
        const int tt = dir ? (TT - 1 - t) : t;
        // stage h (bf16 global -> f32 LDS), 8 rows x 512
        {
            const unsigned short* hsrc =
                h_pp + ((size_t)(dir * 2 + (t & 1)) * BB + bg * 8) * HH;
            for (int i = tid; i < 512; i += 256) {   // 8 rows x 64 chunks(8 vals)
                int bl = i >> 6, ch = i & 63;
                uint4 u = *(const uint4*)(hsrc + bl * HH + ch * 8);
                float4 lo = make_float4(bf_lo(u.x), bf_hi(u.x), bf_lo(u.y), bf_hi(u.y));
                float4 hi = make_float4(bf_lo(u.z), bf_hi(u.z), bf_lo(u.w), bf_hi(u.w));
                *(float4*)&hsf[bl][ch * 8] = lo;
                *(float4*)&hsf[bl][ch * 8 + 4] = hi;
            }
        }
        __syncthreads();

        // prefetch this step's 1KB contiguous xw slice; latency hides under GEMM
        const unsigned xv = *(const unsigned*)(
            xw + (((size_t)jb * 512 + tt) * 32 + bg * 8) * 64 + 2 * tid);

        // GEMM: each wave covers k-range [wv*128, wv*128+128), outputs 8b x 64n
        float acc[4][2] = {{0.f,0.f},{0.f,0.f},{0.f,0.f},{0.f,0.f}};
        for (int kc = wv * 16; kc < wv * 16 + 16; ++kc) {   // 8 k per iter
            uint4 w0 = *(const uint4*)&whhb[ng][kc * 8];
            uint4 w1 = *(const uint4*)&whhb[ng + 32][kc * 8];
            float w00 = bf_lo(w0.x), w01 = bf_hi(w0.x), w02 = bf_lo(w0.y), w03 = bf_hi(w0.y);
            float w04 = bf_lo(w0.z), w05 = bf_hi(w0.z), w06 = bf_lo(w0.w), w07 = bf_hi(w0.w);
            float w10 = bf_lo(w1.x), w11 = bf_hi(w1.x), w12 = bf_lo(w1.y), w13 = bf_hi(w1.y);
            float w14 = bf_lo(w1.z), w15 = bf_hi(w1.z), w16 = bf_lo(w1.w), w17 = bf_hi(w1.w);
#pragma unroll
            for (int i = 0; i < 4; ++i) {
                const int bq = bg2 * 4 + i;
                const float4 ha = *(const float4*)&hsf[bq][kc * 8];
                const float4 hb = *(const float4*)&hsf[bq][kc * 8 + 4];
                acc[i][0] = fmaf(ha.x, w00, fmaf(ha.y, w01, fmaf(ha.z, w02, fmaf(ha.w, w03, acc[i][0]))));
                acc[i][0] = fmaf(hb.x, w04, fmaf(hb.y, w05, fmaf(hb.z, w06, fmaf(hb.w, w07, acc[i][0]))));
                acc[i][1] = fmaf(ha.x, w10, fmaf(ha.y, w11, fmaf(ha.z, w12, fmaf(ha.w, w13, acc[i][1]))));
                acc[i][1] = fmaf(hb.x, w14, fmaf(hb.y, w15, fmaf(hb.z, w16, fmaf(hb.w, w17, acc[i][1]))));
            }
        }
#pragma unroll
        for (int i = 0; i < 4; ++i) {
            part[wv][(bg2 * 4 + i) * 64 + ng] = acc[i][0];
            part[wv][(bg2 * 4 + i) * 64 + ng + 32] = acc[i][1];
        }
        __syncthreads();

        // reduce partials + add prefetched xw (o = 2*tid, 2*tid+1)
        {
            const int o = tid * 2;
            const float2 p0 = *(const float2*)&part[0][o];
            const float2 p1 = *(const float2*)&part[1][o];
            const float2 p2 = *(const float2*)&part[2][o];
            const float2 p3 = *(const float2*)&part[3][o];
            float2 g;
            g.x = p0.x + p1.x + p2.x + p3.x + bf_lo(xv);
            g.y = p0.y + p1.y + p2.y + p3.y + bf_hi(xv);
            *(float2*)&gsh[o] = g;
        }
        __syncthreads();

        // gate nonlinearity + state update (threads 0..127: 8b x 16jj)
        if (tid < 128) {
            int bl = tid >> 4, jj = tid & 15;
            float gi = gsh[bl * 64 + jj];
            float gf = gsh[bl * 64 + 16 + jj];
            float gg = gsh[bl * 64 + 32 + jj];
            float go = gsh[bl * 64 + 48 + jj];
            float si = 1.f / (1.f + expf(-gi));
            float sf = 1.f / (1.f + expf(-gf));
            float so = 1.f / (1.f + expf(-go));
            c_st = sf * c_st + si * tanhf(gg);
            float hv = so * tanhf(c_st);
            unsigned short hb16 = f2bf(hv);
            int b_glob = bg * 8 + bl;
            h_pp[((size_t)(dir * 2 + ((t + 1) & 1)) * BB + b_glob) * HH + js + jj] = hb16;
            outcat[((size_t)b_glob * TT + tt) * 1024 + dir * HH + js + jj] = hb16;
        }
        __syncthreads();

        // group barrier: release add, relaxed polls, single acquire fence
        if (tid == 0) {
            __hip_atomic_fetch_add(mycnt, 1, __ATOMIC_RELEASE, __HIP_MEMORY_SCOPE_AGENT);
            const int target = 32 * (t + 1);
            while (__hip_atomic_load(mycnt, __ATOMIC_RELAXED, __HIP_MEMORY_SCOPE_AGENT) < target) {
                __builtin_amdgcn_s_sleep(1);
            }
            __builtin_amdgcn_fence(__ATOMIC_ACQUIRE, "agent");
        }
        __syncthreads();
    }
}

// ---------------------------------------------------------------------------
// 4) Classifier + log_softmax, transposed write (B,C,T).
__global__ __launch_bounds__(256)
void classifier_k(const unsigned short* __restrict__ hcat, const float* __restrict__ truth,
                  const int* __restrict__ tf, const float* __restrict__ Wc,
                  const float* __restrict__ bc, float* __restrict__ out) {
    __shared__ float feat[8][1024];
    __shared__ float featp[8];
    const int tid = threadIdx.x;
    const int bt0 = blockIdx.x * 8;
    for (int i = tid; i < 8 * 128; i += 256) {   // 8 rows x 128 chunks(8 vals)
        int bl = i >> 7, ch = i & 127;
        uint4 u = *(const uint4*)(hcat + (size_t)(bt0 + bl) * 1024 + ch * 8);
        *(float4*)&feat[bl][ch * 8] = make_float4(bf_lo(u.x), bf_hi(u.x), bf_lo(u.y), bf_hi(u.y));
        *(float4*)&feat[bl][ch * 8 + 4] = make_float4(bf_lo(u.z), bf_hi(u.z), bf_lo(u.w), bf_hi(u.w));
    }
    if (tid < 8) {
        int bt = bt0 + tid;
        int t = bt & 511;
        featp[tid] = (t > 0 && tf[0] != 0) ? truth[bt - 1] : 0.f;
    }
    __syncthreads();
    const int bl = tid >> 5, c = tid & 31;
    const int bt = bt0 + bl;
    float acc = featp[bl] * Wc[c * 1025] + bc[c];
    const float* w = Wc + c * 1025 + 1;
    for (int f4 = 0; f4 < 256; ++f4) {
        const float4 fv = *(const float4*)&feat[bl][f4 * 4];
        acc = fmaf(fv.x, w[f4 * 4 + 0],
              fmaf(fv.y, w[f4 * 4 + 1],
              fmaf(fv.z, w[f4 * 4 + 2],
              fmaf(fv.w, w[f4 * 4 + 3], acc))));
    }
    float m = acc;
#pragma unroll
    for (int mk = 16; mk; mk >>= 1) m = fmaxf(m, __shfl_xor(m, mk));
    float e = expf(acc - m);
    float s = e;
#pragma unroll
    for (int mk = 16; mk; mk >>= 1) s += __shfl_xor(s, mk);
    float lse = m + logf(s);
    int b = bt >> 9, t = bt & 511;
    out[((size_t)b * CC + c) * TT + t] = acc - lse;
}

// ---------------------------------------------------------------------------
extern "C" void kernel_launch(void* const* d_in, const int* in_sizes, int n_in,
                              void* d_out, int out_size, void* d_ws, size_t ws_size,
                              hipStream_t stream) {
    const int* x = (const int*)d_in[0];
    const float* truth = (const float*)d_in[1];
    const int* tf = (const int*)d_in[2];
    const float* emb = (const float*)d_in[3];
    const float* Wih0f = (const float*)d_in[4];
    const float* Whh0f = (const float*)d_in[5];
    const float* bih0f = (const float*)d_in[6];
    const float* bhh0f = (const float*)d_in[7];
    const float* Wih0b = (const float*)d_in[8];
    const float* Whh0b = (const float*)d_in[9];
    const float* bih0b = (const float*)d_in[10];
    const float* bhh0b = (const float*)d_in[11];
    const float* Wih1f = (const float*)d_in[12];
    const float* Whh1f = (const float*)d_in[13];
    const float* bih1f = (const float*)d_in[14];
    const float* bhh1f = (const float*)d_in[15];
    const float* Wih1b = (const float*)d_in[16];
    const float* Whh1b = (const float*)d_in[17];
    const float* bih1b = (const float*)d_in[18];
    const float* bhh1b = (const float*)d_in[19];
    const float* Wc = (const float*)d_in[20];
    const float* bc = (const float*)d_in[21];
    float* out = (float*)d_out;

    // ws layout (bytes)
    const size_t off_h0  = 0;                       // (B,T,512) bf16 : 16 MB
    const size_t off_xwf = 16777216;                // perm (32,512,32,64) bf16: 64 MB
    const size_t off_xwb = off_xwf + 67108864;
    const size_t off_hc1 = off_xwb + 67108864;      // (B,T,1024) bf16: 32 MB
    const size_t off_hc2 = off_hc1 + 33554432;
    const size_t off_hpp = off_hc2 + 33554432;      // 128 KB
    const size_t off_cnt = off_hpp + 131072;        // 8 x 1KB counters
    const size_t need = off_cnt + 8192;
    if (ws_size < need) return;

    char* ws = (char*)d_ws;
    unsigned short* h0  = (unsigned short*)(ws + off_h0);
    unsigned short* xwf = (unsigned short*)(ws + off_xwf);
    unsigned short* xwb = (unsigned short*)(ws + off_xwb);
    unsigned short* hc1 = (unsigned short*)(ws + off_hc1);
    unsigned short* hc2 = (unsigned short*)(ws + off_hc2);
    unsigned short* hpp = (unsigned short*)(ws + off_hpp);
    int* cnt = (int*)(ws + off_cnt);

    embed_k<<<8192, 256, 0, stream>>>(x, emb, h0);

    // layer 0
    gemm_xw<<<8192, 256, 0, stream>>>(h0, Wih0f, bih0f, bhh0f, xwf, BB * TT, EE);
    gemm_xw<<<8192, 256, 0, stream>>>(h0, Wih0b, bih0b, bhh0b, xwb, BB * TT, EE);
    (void)hipMemsetAsync(ws + off_hpp, 0, 131072 + 8192, stream);
    lstm_scan<<<256, 256, 0, stream>>>(Whh0f, Whh0b, xwf, xwb, hc1, hpp, cnt);

    // layer 1
    gemm_xw<<<8192, 256, 0, stream>>>(hc1, Wih1f, bih1f, bhh1f, xwf, BB * TT, 1024);
    gemm_xw<<<8192, 256, 0, stream>>>(hc1, Wih1b, bih1b, bhh1b, xwb, BB * TT, 1024);
    (void)hipMemsetAsync(ws + off_hpp, 0, 131072 + 8192, stream);
    lstm_scan<<<256, 256, 0, stream>>>(Whh1f, Whh1b, xwf, xwb, hc2, hpp, cnt);

    classifier_k<<<2048, 256, 0, stream>>>(hc2, truth, tf, Wc, bc, out);
}

// Round 4
// 11539.242 us; speedup vs baseline: 1.6752x; 1.1302x over previous
//
#include <hip/hip_runtime.h>

// ---------------------------------------------------------------------------
// LSTM_NER_TeacherForcing: B=32, T=512, E=512, H=512, V=50000, C=32, L=2
// embed -> [mfma gemm xw -> persistent scan] x2 -> classifier
// Round 4: (a) barrier = per-block release-store flags (128B apart) + wave0
//          parallel poll (no RMW contention); (b) per-wave h staging (each
//          wave stages only its own k-quarter -> one less syncthreads);
//          (c) outcat write deferred past the flag release; (d) __expf gates.
// ---------------------------------------------------------------------------

#define BB 32
#define TT 512
#define EE 512
#define HH 512
#define NG 2048   // 4*H gate rows
#define CC 32

typedef __attribute__((ext_vector_type(8))) short short8v;
typedef __attribute__((ext_vector_type(4))) float float4v;

__device__ __forceinline__ float bf2f(unsigned short u) {
    return __uint_as_float(((unsigned)u) << 16);
}
__device__ __forceinline__ float bf_lo(unsigned u) { return __uint_as_float(u << 16); }
__device__ __forceinline__ float bf_hi(unsigned u) { return __uint_as_float(u & 0xffff0000u); }
__device__ __forceinline__ unsigned short f2bf(float f) {
    unsigned u = __float_as_uint(f);
    u += 0x7fffu + ((u >> 16) & 1u);   // RNE
    return (unsigned short)(u >> 16);
}
__device__ __forceinline__ float fast_sigmoid(float x) {
    return 1.f / (1.f + __expf(-x));
}
__device__ __forceinline__ float fast_tanh(float x) {
    x = fminf(fmaxf(x, -15.f), 15.f);
    float e = __expf(2.f * x);
    return (e - 1.f) / (e + 1.f);
}

// ---------------------------------------------------------------------------
// 1) Embedding gather: h0[b,t,e] = emb[x[b,t]][e]  (f32 -> bf16)
__global__ __launch_bounds__(256)
void embed_k(const int* __restrict__ x, const float* __restrict__ emb,
             unsigned short* __restrict__ h0) {
    int idx = blockIdx.x * 256 + threadIdx.x;    // one float4 each
    int row = idx >> 7;                          // E/4 = 128 chunks per row
    int c4  = idx & 127;
    int tok = x[row];
    float4 v = *(const float4*)(emb + ((size_t)tok << 9) + (c4 << 2));
    ushort4 o;
    o.x = f2bf(v.x); o.y = f2bf(v.y); o.z = f2bf(v.z); o.w = f2bf(v.w);
    *(ushort4*)(h0 + ((size_t)row << 9) + (c4 << 2)) = o;
}

// ---------------------------------------------------------------------------
// 2) Input GEMM via MFMA, output written PERMUTED for the scan:
// xwp[((jb*512 + t)*32 + b)*64 + gate*16 + jj], jb=(n&511)>>4, gate=n>>9, jj=n&15
__global__ __launch_bounds__(256)
void gemm_xw(const unsigned short* __restrict__ A, const float* __restrict__ Bw,
             const float* __restrict__ bih, const float* __restrict__ bhh,
             unsigned short* __restrict__ Cp, int M, int K) {
    __shared__ unsigned short As[64][40];   // row-major (m,k), pad to 40
    __shared__ unsigned short Bs[64][40];   // (n,k)
    const int bn = blockIdx.x & 31, bm = blockIdx.x >> 5;
    const int tid = threadIdx.x;
    const int wv = tid >> 6, lane = tid & 63;
    const int wm = (wv >> 1) * 32, wn = (wv & 1) * 32;
    const int sr = tid >> 2, sk = (tid & 3) * 8;   // staging: row, k-chunk of 8
    const int fr = lane & 15, fk = (lane >> 4) * 8;

    float4v acc[2][2];
#pragma unroll
    for (int i = 0; i < 2; ++i)
#pragma unroll
        for (int j = 0; j < 2; ++j) acc[i][j] = (float4v)(0.0f);

    for (int k0 = 0; k0 < K; k0 += 32) {
        // stage A (bf16 copy, 16B/thread)
        *(uint4*)&As[sr][sk] = *(const uint4*)(A + (size_t)(bm * 64 + sr) * K + k0 + sk);
        // stage B (f32 -> bf16)
        const float* bp = Bw + (size_t)(bn * 64 + sr) * K + k0 + sk;
        const float4 b0 = *(const float4*)bp;
        const float4 b1 = *(const float4*)(bp + 4);
        ushort4 o0 = {f2bf(b0.x), f2bf(b0.y), f2bf(b0.z), f2bf(b0.w)};
        ushort4 o1 = {f2bf(b1.x), f2bf(b1.y), f2bf(b1.z), f2bf(b1.w)};
        *(ushort4*)&Bs[sr][sk] = o0;
        *(ushort4*)&Bs[sr][sk + 4] = o1;
        __syncthreads();

        short8v a0 = *(const short8v*)&As[wm + fr][fk];
        short8v a1 = *(const short8v*)&As[wm + 16 + fr][fk];
        short8v bb0 = *(const short8v*)&Bs[wn + fr][fk];
        short8v bb1 = *(const short8v*)&Bs[wn + 16 + fr][fk];
        acc[0][0] = __builtin_amdgcn_mfma_f32_16x16x32_bf16(a0, bb0, acc[0][0], 0, 0, 0);
        acc[0][1] = __builtin_amdgcn_mfma_f32_16x16x32_bf16(a0, bb1, acc[0][1], 0, 0, 0);
        acc[1][0] = __builtin_amdgcn_mfma_f32_16x16x32_bf16(a1, bb0, acc[1][0], 0, 0, 0);
        acc[1][1] = __builtin_amdgcn_mfma_f32_16x16x32_bf16(a1, bb1, acc[1][1], 0, 0, 0);
        __syncthreads();
    }

    const int r4 = (lane >> 4) * 4;
#pragma unroll
    for (int nt = 0; nt < 2; ++nt) {
        const int nglob = bn * 64 + wn + nt * 16 + fr;
        const float bias = bih[nglob] + bhh[nglob];
        const int gate = nglob >> 9;
        const int jbv = (nglob & 511) >> 4;
        const int loc = gate * 16 + (nglob & 15);
#pragma unroll
        for (int mt = 0; mt < 2; ++mt) {
#pragma unroll
            for (int i = 0; i < 4; ++i) {
                const int mglob = bm * 64 + wm + mt * 16 + r4 + i;
                const int b = mglob >> 9, t = mglob & 511;
                Cp[(((size_t)jbv * 512 + t) * 32 + b) * 64 + loc] =
                    f2bf(acc[mt][nt][i] + bias);
            }
        }
    }
}

// ---------------------------------------------------------------------------
// 3) Persistent bidirectional LSTM scan for one layer.
// grid = 256 blocks: grp = blk&7 (same-XCD group heuristic), jb = blk>>3.
// Barrier: per-block flag (128B apart) release-store + wave0 parallel poll.
__global__ __launch_bounds__(256, 1)
void lstm_scan(const float* __restrict__ WhhF, const float* __restrict__ WhhB,
               const unsigned short* __restrict__ xwF, const unsigned short* __restrict__ xwB,
               unsigned short* __restrict__ outcat,   // (B,T,1024) bf16
               unsigned short* __restrict__ h_pp,     // [dir][parity][32][512] bf16
               int* __restrict__ cnt) {               // flags: 8 grp x 32 blk x 128B
    __shared__ unsigned short whhb[64][520];  // 66.5 KB
    __shared__ float hsf[8][520];             // 16.6 KB
    __shared__ float part[4][512];            // 8 KB
    __shared__ float gsh[512];                // 2 KB

    const int blk = blockIdx.x;
    const int grp = blk & 7, jb = blk >> 3;
    const int bg = grp & 3, dir = grp >> 2;
    const int tid = threadIdx.x;
    const float* Whh = dir ? WhhB : WhhF;
    const unsigned short* xw = dir ? xwB : xwF;
    const int js = jb << 4;
    int* const myflags = cnt + grp * 32 * 32;   // flag j at myflags[j*32]

    // Preload Whh slice: local row r = gate*16 + jj  <->  global row gate*512 + js + jj
    for (int i = tid; i < 64 * 128; i += 256) {
        int r = i >> 7, c4 = i & 127;
        int R = ((r >> 4) << 9) + js + (r & 15);
        float4 v = *(const float4*)(Whh + (size_t)R * HH + c4 * 4);
        ushort4 w;
        w.x = f2bf(v.x); w.y = f2bf(v.y); w.z = f2bf(v.z); w.w = f2bf(v.w);
        *(ushort4*)&whhb[r][c4 * 4] = w;
    }
    float c_st = 0.f;
    const int wv = tid >> 6, lane = tid & 63, bg2 = lane >> 5, ng = lane & 31;
    const int st_bl = lane >> 3, st_co = (lane & 7) * 16;   // staging coords
    __syncthreads();

    for (int t = 0; t < TT; ++t) {
        const int tt = dir ? (TT - 1 - t) : t;

        // per-wave stage: wave wv stages h cols [wv*128, wv*128+128) (its own
        // GEMM k-range) -> no cross-wave barrier needed.
        {
            const unsigned short* p =
                h_pp + ((size_t)(dir * 2 + (t & 1)) * BB + bg * 8 + st_bl) * HH
                + wv * 128 + st_co;
            uint4 u0 = *(const uint4*)p;
            uint4 u1 = *(const uint4*)(p + 8);
            float* dst = &hsf[st_bl][wv * 128 + st_co];
            *(float4*)dst       = make_float4(bf_lo(u0.x), bf_hi(u0.x), bf_lo(u0.y), bf_hi(u0.y));
            *(float4*)(dst + 4) = make_float4(bf_lo(u0.z), bf_hi(u0.z), bf_lo(u0.w), bf_hi(u0.w));
            *(float4*)(dst + 8) = make_float4(bf_lo(u1.x), bf_hi(u1.x), bf_lo(u1.y), bf_hi(u1.y));
            *(float4*)(dst + 12)= make_float4(bf_lo(u1.z), bf_hi(u1.z), bf_lo(u1.w), bf_hi(u1.w));
        }

        // prefetch this step's 1KB contiguous xw slice; latency hides under GEMM
        const unsigned xv = *(const unsigned*)(
            xw + (((size_t)jb * 512 + tt) * 32 + bg * 8) * 64 + 2 * tid);

        // GEMM: wave wv covers k-range [wv*128, wv*128+128), outputs 8b x 64n
        float acc[4][2] = {{0.f,0.f},{0.f,0.f},{0.f,0.f},{0.f,0.f}};
        for (int kc = wv * 16; kc < wv * 16 + 16; ++kc) {   // 8 k per iter
            uint4 w0 = *(const uint4*)&whhb[ng][kc * 8];
            uint4 w1 = *(const uint4*)&whhb[ng + 32][kc * 8];
            float w00 = bf_lo(w0.x), w01 = bf_hi(w0.x), w02 = bf_lo(w0.y), w03 = bf_hi(w0.y);
            float w04 = bf_lo(w0.z), w05 = bf_hi(w0.z), w06 = bf_lo(w0.w), w07 = bf_hi(w0.w);
            float w10 = bf_lo(w1.x), w11 = bf_hi(w1.x), w12 = bf_lo(w1.y), w13 = bf_hi(w1.y);
            float w14 = bf_lo(w1.z), w15 = bf_hi(w1.z), w16 = bf_lo(w1.w), w17 = bf_hi(w1.w);
#pragma unroll
            for (int i = 0; i < 4; ++i) {
                const int bq = bg2 * 4 + i;
                const float4 ha = *(const float4*)&hsf[bq][kc * 8];
                const float4 hb = *(const float4*)&hsf[bq][kc * 8 + 4];
                acc[i][0] = fmaf(ha.x, w00, fmaf(ha.y, w01, fmaf(ha.z, w02, fmaf(ha.w, w03, acc[i][0]))));
                acc[i][0] = fmaf(hb.x, w04, fmaf(hb.y, w05, fmaf(hb.z, w06, fmaf(hb.w, w07, acc[i][0]))));
                acc[i][1] = fmaf(ha.x, w10, fmaf(ha.y, w11, fmaf(ha.z, w12, fmaf(ha.w, w13, acc[i][1]))));
                acc[i][1] = fmaf(hb.x, w14, fmaf(hb.y, w15, fmaf(hb.z, w16, fmaf(hb.w, w17, acc[i][1]))));
            }
        }
#pragma unroll
        for (int i = 0; i < 4; ++i) {
            part[wv][(bg2 * 4 + i) * 64 + ng] = acc[i][0];
            part[wv][(bg2 * 4 + i) * 64 + ng + 32] = acc[i][1];
        }
        __syncthreads();

        // reduce partials + add prefetched xw (o = 2*tid, 2*tid+1)
        {
            const int o = tid * 2;
            const float2 p0 = *(const float2*)&part[0][o];
            const float2 p1 = *(const float2*)&part[1][o];
            const float2 p2 = *(const float2*)&part[2][o];
            const float2 p3 = *(const float2*)&part[3][o];
            float2 g;
            g.x = p0.x + p1.x + p2.x + p3.x + bf_lo(xv);
            g.y = p0.y + p1.y + p2.y + p3.y + bf_hi(xv);
            *(float2*)&gsh[o] = g;
        }
        __syncthreads();

        // gate nonlinearity + state update (threads 0..127: 8b x 16jj)
        unsigned short hb16 = 0;
        int b_glob = 0;
        if (tid < 128) {
            int bl = tid >> 4, jj = tid & 15;
            float gi = gsh[bl * 64 + jj];
            float gf = gsh[bl * 64 + 16 + jj];
            float gg = gsh[bl * 64 + 32 + jj];
            float go = gsh[bl * 64 + 48 + jj];
            float si = fast_sigmoid(gi);
            float sf = fast_sigmoid(gf);
            float so = fast_sigmoid(go);
            c_st = sf * c_st + si * fast_tanh(gg);
            float hv = so * fast_tanh(c_st);
            hb16 = f2bf(hv);
            b_glob = bg * 8 + bl;
            h_pp[((size_t)(dir * 2 + ((t + 1) & 1)) * BB + b_glob) * HH + js + jj] = hb16;
        }
        __syncthreads();   // drains every wave's h_pp stores (vmcnt0 before s_barrier)

        if (t != TT - 1) {
            // announce step completion: private flag, no write contention
            if (tid == 0) {
                __hip_atomic_store(&myflags[jb * 32], t + 1,
                                   __ATOMIC_RELEASE, __HIP_MEMORY_SCOPE_AGENT);
            }
            // deferred outcat write (not on the sync critical path)
            if (tid < 128) {
                int jj = tid & 15;
                outcat[((size_t)b_glob * TT + tt) * 1024 + dir * HH + js + jj] = hb16;
            }
            // wave0: poll all 32 flags in parallel (one per lane, relaxed), then acquire
            if (tid < 64) {
                const int l = tid & 31;
                const int target = t + 1;
                while (__hip_atomic_load(&myflags[l * 32], __ATOMIC_RELAXED,
                                         __HIP_MEMORY_SCOPE_AGENT) < target) {
                    __builtin_amdgcn_s_sleep(1);
                }
                __builtin_amdgcn_fence(__ATOMIC_ACQUIRE, "agent");
            }
            __syncthreads();
        } else {
            if (tid < 128) {
                int jj = tid & 15;
                outcat[((size_t)b_glob * TT + tt) * 1024 + dir * HH + js + jj] = hb16;
            }
        }
    }
}

// ---------------------------------------------------------------------------
// 4) Classifier + log_softmax, transposed write (B,C,T).
__global__ __launch_bounds__(256)
void classifier_k(const unsigned short* __restrict__ hcat, const float* __restrict__ truth,
                  const int* __restrict__ tf, const float* __restrict__ Wc,
                  const float* __restrict__ bc, float* __restrict__ out) {
    __shared__ float feat[8][1024];
    __shared__ float featp[8];
    const int tid = threadIdx.x;
    const int bt0 = blockIdx.x * 8;
    for (int i = tid; i < 8 * 128; i += 256) {   // 8 rows x 128 chunks(8 vals)
        int bl = i >> 7, ch = i & 127;
        uint4 u = *(const uint4*)(hcat + (size_t)(bt0 + bl) * 1024 + ch * 8);
        *(float4*)&feat[bl][ch * 8] = make_float4(bf_lo(u.x), bf_hi(u.x), bf_lo(u.y), bf_hi(u.y));
        *(float4*)&feat[bl][ch * 8 + 4] = make_float4(bf_lo(u.z), bf_hi(u.z), bf_lo(u.w), bf_hi(u.w));
    }
    if (tid < 8) {
        int bt = bt0 + tid;
        int t = bt & 511;
        featp[tid] = (t > 0 && tf[0] != 0) ? truth[bt - 1] : 0.f;
    }
    __syncthreads();
    const int bl = tid >> 5, c = tid & 31;
    const int bt = bt0 + bl;
    float acc = featp[bl] * Wc[c * 1025] + bc[c];
    const float* w = Wc + c * 1025 + 1;
    for (int f4 = 0; f4 < 256; ++f4) {
        const float4 fv = *(const float4*)&feat[bl][f4 * 4];
        acc = fmaf(fv.x, w[f4 * 4 + 0],
              fmaf(fv.y, w[f4 * 4 + 1],
              fmaf(fv.z, w[f4 * 4 + 2],
              fmaf(fv.w, w[f4 * 4 + 3], acc))));
    }
    float m = acc;
#pragma unroll
    for (int mk = 16; mk; mk >>= 1) m = fmaxf(m, __shfl_xor(m, mk));
    float e = expf(acc - m);
    float s = e;
#pragma unroll
    for (int mk = 16; mk; mk >>= 1) s += __shfl_xor(s, mk);
    float lse = m + logf(s);
    int b = bt >> 9, t = bt & 511;
    out[((size_t)b * CC + c) * TT + t] = acc - lse;
}

// ---------------------------------------------------------------------------
extern "C" void kernel_launch(void* const* d_in, const int* in_sizes, int n_in,
                              void* d_out, int out_size, void* d_ws, size_t ws_size,
                              hipStream_t stream) {
    const int* x = (const int*)d_in[0];
    const float* truth = (const float*)d_in[1];
    const int* tf = (const int*)d_in[2];
    const float* emb = (const float*)d_in[3];
    const float* Wih0f = (const float*)d_in[4];
    const float* Whh0f = (const float*)d_in[5];
    const float* bih0f = (const float*)d_in[6];
    const float* bhh0f = (const float*)d_in[7];
    const float* Wih0b = (const float*)d_in[8];
    const float* Whh0b = (const float*)d_in[9];
    const float* bih0b = (const float*)d_in[10];
    const float* bhh0b = (const float*)d_in[11];
    const float* Wih1f = (const float*)d_in[12];
    const float* Whh1f = (const float*)d_in[13];
    const float* bih1f = (const float*)d_in[14];
    const float* bhh1f = (const float*)d_in[15];
    const float* Wih1b = (const float*)d_in[16];
    const float* Whh1b = (const float*)d_in[17];
    const float* bih1b = (const float*)d_in[18];
    const float* bhh1b = (const float*)d_in[19];
    const float* Wc = (const float*)d_in[20];
    const float* bc = (const float*)d_in[21];
    float* out = (float*)d_out;

    // ws layout (bytes)
    const size_t off_h0  = 0;                       // (B,T,512) bf16 : 16 MB
    const size_t off_xwf = 16777216;                // perm (32,512,32,64) bf16: 64 MB
    const size_t off_xwb = off_xwf + 67108864;
    const size_t off_hc1 = off_xwb + 67108864;      // (B,T,1024) bf16: 32 MB
    const size_t off_hc2 = off_hc1 + 33554432;
    const size_t off_hpp = off_hc2 + 33554432;      // 128 KB
    const size_t off_cnt = off_hpp + 131072;        // flags 8*32*128B = 32 KB
    const size_t need = off_cnt + 32768;
    if (ws_size < need) return;

    char* ws = (char*)d_ws;
    unsigned short* h0  = (unsigned short*)(ws + off_h0);
    unsigned short* xwf = (unsigned short*)(ws + off_xwf);
    unsigned short* xwb = (unsigned short*)(ws + off_xwb);
    unsigned short* hc1 = (unsigned short*)(ws + off_hc1);
    unsigned short* hc2 = (unsigned short*)(ws + off_hc2);
    unsigned short* hpp = (unsigned short*)(ws + off_hpp);
    int* cnt = (int*)(ws + off_cnt);

    embed_k<<<8192, 256, 0, stream>>>(x, emb, h0);

    // layer 0
    gemm_xw<<<8192, 256, 0, stream>>>(h0, Wih0f, bih0f, bhh0f, xwf, BB * TT, EE);
    gemm_xw<<<8192, 256, 0, stream>>>(h0, Wih0b, bih0b, bhh0b, xwb, BB * TT, EE);
    (void)hipMemsetAsync(ws + off_hpp, 0, 131072 + 32768, stream);
    lstm_scan<<<256, 256, 0, stream>>>(Whh0f, Whh0b, xwf, xwb, hc1, hpp, cnt);

    // layer 1
    gemm_xw<<<8192, 256, 0, stream>>>(hc1, Wih1f, bih1f, bhh1f, xwf, BB * TT, 1024);
    gemm_xw<<<8192, 256, 0, stream>>>(hc1, Wih1b, bih1b, bhh1b, xwb, BB * TT, 1024);
    (void)hipMemsetAsync(ws + off_hpp, 0, 131072 + 32768, stream);
    lstm_scan<<<256, 256, 0, stream>>>(Whh1f, Whh1b, xwf, xwb, hc2, hpp, cnt);

    classifier_k<<<2048, 256, 0, stream>>>(hc2, truth, tf, Wc, bc, out);
}

// Round 5
// 7338.325 us; speedup vs baseline: 2.6342x; 1.5725x over previous
//
#include <hip/hip_runtime.h>

// ---------------------------------------------------------------------------
// LSTM_NER_TeacherForcing: B=32, T=512, E=512, H=512, V=50000, C=32, L=2
// embed -> [mfma gemm xw -> persistent scan] x2 -> classifier
// Round 5: scan rewritten:
//   - all cross-block state (h, flags) moves via agent-scope ATOMIC ops (sc1,
//     coherence point) -> NO acquire fences, no L2 invalidates per step;
//   - scan GEMM = MFMA 16x16x32 with Whh held in VGPRs (16 B-frags/wave,
//     wave = one gate type); h staged to LDS with XOR swizzle;
//   - no cross-wave K-reduction (each wave owns full K=512).
// ---------------------------------------------------------------------------

#define BB 32
#define TT 512
#define EE 512
#define HH 512
#define NG 2048   // 4*H gate rows
#define CC 32

typedef __attribute__((ext_vector_type(8))) short short8v;
typedef __attribute__((ext_vector_type(4))) float float4v;

__device__ __forceinline__ float bf2f(unsigned short u) {
    return __uint_as_float(((unsigned)u) << 16);
}
__device__ __forceinline__ float bf_lo(unsigned u) { return __uint_as_float(u << 16); }
__device__ __forceinline__ float bf_hi(unsigned u) { return __uint_as_float(u & 0xffff0000u); }
__device__ __forceinline__ unsigned short f2bf(float f) {
    unsigned u = __float_as_uint(f);
    u += 0x7fffu + ((u >> 16) & 1u);   // RNE
    return (unsigned short)(u >> 16);
}
__device__ __forceinline__ float fast_sigmoid(float x) {
    return 1.f / (1.f + __expf(-x));
}
__device__ __forceinline__ float fast_tanh(float x) {
    x = fminf(fmaxf(x, -15.f), 15.f);
    float e = __expf(2.f * x);
    return (e - 1.f) / (e + 1.f);
}

// ---------------------------------------------------------------------------
// 1) Embedding gather: h0[b,t,e] = emb[x[b,t]][e]  (f32 -> bf16)
__global__ __launch_bounds__(256)
void embed_k(const int* __restrict__ x, const float* __restrict__ emb,
             unsigned short* __restrict__ h0) {
    int idx = blockIdx.x * 256 + threadIdx.x;    // one float4 each
    int row = idx >> 7;                          // E/4 = 128 chunks per row
    int c4  = idx & 127;
    int tok = x[row];
    float4 v = *(const float4*)(emb + ((size_t)tok << 9) + (c4 << 2));
    ushort4 o;
    o.x = f2bf(v.x); o.y = f2bf(v.y); o.z = f2bf(v.z); o.w = f2bf(v.w);
    *(ushort4*)(h0 + ((size_t)row << 9) + (c4 << 2)) = o;
}

// ---------------------------------------------------------------------------
// 2) Input GEMM via MFMA, output written PERMUTED for the scan:
// xwp[((jb*512 + t)*32 + b)*64 + gate*16 + jj], jb=(n&511)>>4, gate=n>>9, jj=n&15
__global__ __launch_bounds__(256)
void gemm_xw(const unsigned short* __restrict__ A, const float* __restrict__ Bw,
             const float* __restrict__ bih, const float* __restrict__ bhh,
             unsigned short* __restrict__ Cp, int M, int K) {
    __shared__ unsigned short As[64][40];   // row-major (m,k), pad to 40
    __shared__ unsigned short Bs[64][40];   // (n,k)
    const int bn = blockIdx.x & 31, bm = blockIdx.x >> 5;
    const int tid = threadIdx.x;
    const int wv = tid >> 6, lane = tid & 63;
    const int wm = (wv >> 1) * 32, wn = (wv & 1) * 32;
    const int sr = tid >> 2, sk = (tid & 3) * 8;   // staging: row, k-chunk of 8
    const int fr = lane & 15, fk = (lane >> 4) * 8;

    float4v acc[2][2];
#pragma unroll
    for (int i = 0; i < 2; ++i)
#pragma unroll
        for (int j = 0; j < 2; ++j) acc[i][j] = (float4v)(0.0f);

    for (int k0 = 0; k0 < K; k0 += 32) {
        *(uint4*)&As[sr][sk] = *(const uint4*)(A + (size_t)(bm * 64 + sr) * K + k0 + sk);
        const float* bp = Bw + (size_t)(bn * 64 + sr) * K + k0 + sk;
        const float4 b0 = *(const float4*)bp;
        const float4 b1 = *(const float4*)(bp + 4);
        ushort4 o0 = {f2bf(b0.x), f2bf(b0.y), f2bf(b0.z), f2bf(b0.w)};
        ushort4 o1 = {f2bf(b1.x), f2bf(b1.y), f2bf(b1.z), f2bf(b1.w)};
        *(ushort4*)&Bs[sr][sk] = o0;
        *(ushort4*)&Bs[sr][sk + 4] = o1;
        __syncthreads();

        short8v a0 = *(const short8v*)&As[wm + fr][fk];
        short8v a1 = *(const short8v*)&As[wm + 16 + fr][fk];
        short8v bb0 = *(const short8v*)&Bs[wn + fr][fk];
        short8v bb1 = *(const short8v*)&Bs[wn + 16 + fr][fk];
        acc[0][0] = __builtin_amdgcn_mfma_f32_16x16x32_bf16(a0, bb0, acc[0][0], 0, 0, 0);
        acc[0][1] = __builtin_amdgcn_mfma_f32_16x16x32_bf16(a0, bb1, acc[0][1], 0, 0, 0);
        acc[1][0] = __builtin_amdgcn_mfma_f32_16x16x32_bf16(a1, bb0, acc[1][0], 0, 0, 0);
        acc[1][1] = __builtin_amdgcn_mfma_f32_16x16x32_bf16(a1, bb1, acc[1][1], 0, 0, 0);
        __syncthreads();
    }

    const int r4 = (lane >> 4) * 4;
#pragma unroll
    for (int nt = 0; nt < 2; ++nt) {
        const int nglob = bn * 64 + wn + nt * 16 + fr;
        const float bias = bih[nglob] + bhh[nglob];
        const int gate = nglob >> 9;
        const int jbv = (nglob & 511) >> 4;
        const int loc = gate * 16 + (nglob & 15);
#pragma unroll
        for (int mt = 0; mt < 2; ++mt) {
#pragma unroll
            for (int i = 0; i < 4; ++i) {
                const int mglob = bm * 64 + wm + mt * 16 + r4 + i;
                const int b = mglob >> 9, t = mglob & 511;
                Cp[(((size_t)jbv * 512 + t) * 32 + b) * 64 + loc] =
                    f2bf(acc[mt][nt][i] + bias);
            }
        }
    }
}

// ---------------------------------------------------------------------------
// 3) Persistent bidirectional LSTM scan. grid = 256 blocks, 256 thr (4 waves).
// blk: grp = blk&7 (dir*4+bg, same-XCD heuristic), jb = blk>>3 (16 h-cols).
// Wave w = gate type w: holds Whh[w*512+js .. +16][0..512) as 16 MFMA B-frags
// in VGPRs. h state crosses blocks as packed uint (2xbf16) agent-atomics.
__global__ __launch_bounds__(256, 1)
void lstm_scan(const float* __restrict__ WhhF, const float* __restrict__ WhhB,
               const unsigned short* __restrict__ xwF, const unsigned short* __restrict__ xwB,
               unsigned short* __restrict__ outcat,   // (B,T,1024) bf16
               unsigned int* __restrict__ h_pp,       // [dir*2+par][32][256] uint
               int* __restrict__ cnt) {               // flags: 8 grp x 32 blk x 128B
    __shared__ __align__(16) unsigned char hs[16384];  // bf16 [16 rows][512 k], swizzled
    __shared__ float gsh[4][8][16];
    __shared__ unsigned xsh[256];

    const int blk = blockIdx.x;
    const int grp = blk & 7, jb = blk >> 3;
    const int bg = grp & 3, dir = grp >> 2;
    const int tid = threadIdx.x;
    const int wv = tid >> 6, lane = tid & 63;
    const float* Whh = dir ? WhhB : WhhF;
    const unsigned short* xw = dir ? xwB : xwF;
    const int js = jb << 4;
    int* const myflags = cnt + grp * 32 * 32;   // flag j at myflags[j*32]

    // ---- preload weights into registers: wave wv = gate type wv ----
    // B-frag kk: lane l -> W[wv*512+js+(l&15)][kk*32+(l>>4)*8 + j], j=0..7
    short8v bw[16];
    {
        const float* wrow = Whh + (size_t)(wv * 512 + js + (lane & 15)) * HH
                            + (lane >> 4) * 8;
#pragma unroll
        for (int kk = 0; kk < 16; ++kk) {
            const float4 f0 = *(const float4*)(wrow + kk * 32);
            const float4 f1 = *(const float4*)(wrow + kk * 32 + 4);
            short8v b;
            b[0] = (short)f2bf(f0.x); b[1] = (short)f2bf(f0.y);
            b[2] = (short)f2bf(f0.z); b[3] = (short)f2bf(f0.w);
            b[4] = (short)f2bf(f1.x); b[5] = (short)f2bf(f1.y);
            b[6] = (short)f2bf(f1.z); b[7] = (short)f2bf(f1.w);
            bw[kk] = b;
        }
    }

    // zero hs rows 8..15 once (A-frag rows 8-15 are never re-written)
    for (int i = tid; i < 8 * 64; i += 256) {
        int r = 8 + (i >> 6), c = i & 63;
        *(uint4*)(hs + r * 1024 + ((c * 16) ^ ((r & 7) << 4))) = make_uint4(0, 0, 0, 0);
    }

    float c_st = 0.f;
    // stage coords: thread -> row tid>>5 (0..7), uint chunk (tid&31)*8
    const int srow = tid >> 5, schk = tid & 31;
    const unsigned swz_w = (srow & 7) << 4;
    // A-frag read coords
    const int arow = lane & 15, ag16 = (lane >> 4) * 16;
    const unsigned swz_r = (arow & 7) << 4;
    __syncthreads();

    for (int t = 0; t < TT; ++t) {
        const int tt = dir ? (TT - 1 - t) : t;
        const int dp_r = dir * 2 + (t & 1);

        // xw slice for this step (1KB contiguous): one uint per thread
        const unsigned xv = *(const unsigned*)(
            xw + (((size_t)jb * 512 + tt) * 32 + bg * 8) * 64 + 2 * tid);

        // ---- stage h: 8 agent-atomic uint loads/thread (fresh via sc1) ----
        {
            const unsigned int* hsrc =
                h_pp + ((size_t)dp_r * BB + bg * 8 + srow) * 256 + schk * 8;
            unsigned u0 = __hip_atomic_load(hsrc + 0, __ATOMIC_RELAXED, __HIP_MEMORY_SCOPE_AGENT);
            unsigned u1 = __hip_atomic_load(hsrc + 1, __ATOMIC_RELAXED, __HIP_MEMORY_SCOPE_AGENT);
            unsigned u2 = __hip_atomic_load(hsrc + 2, __ATOMIC_RELAXED, __HIP_MEMORY_SCOPE_AGENT);
            unsigned u3 = __hip_atomic_load(hsrc + 3, __ATOMIC_RELAXED, __HIP_MEMORY_SCOPE_AGENT);
            unsigned u4 = __hip_atomic_load(hsrc + 4, __ATOMIC_RELAXED, __HIP_MEMORY_SCOPE_AGENT);
            unsigned u5 = __hip_atomic_load(hsrc + 5, __ATOMIC_RELAXED, __HIP_MEMORY_SCOPE_AGENT);
            unsigned u6 = __hip_atomic_load(hsrc + 6, __ATOMIC_RELAXED, __HIP_MEMORY_SCOPE_AGENT);
            unsigned u7 = __hip_atomic_load(hsrc + 7, __ATOMIC_RELAXED, __HIP_MEMORY_SCOPE_AGENT);
            xsh[tid] = xv;
            unsigned off0 = srow * 1024 + (((2 * schk) * 16) ^ swz_w);
            unsigned off1 = srow * 1024 + (((2 * schk + 1) * 16) ^ swz_w);
            *(uint4*)(hs + off0) = make_uint4(u0, u1, u2, u3);
            *(uint4*)(hs + off1) = make_uint4(u4, u5, u6, u7);
        }
        __syncthreads();   // (1) h staged

        // ---- MFMA: wave wv computes gates[wv][b 0..7][jj 0..15] over K=512 ----
        {
            float4v a0 = (float4v)(0.0f), a1 = (float4v)(0.0f);
#pragma unroll
            for (int kk = 0; kk < 16; kk += 2) {
                short8v af0 = *(const short8v*)(hs + arow * 1024 +
                                  (((kk * 64) + ag16) ^ swz_r));
                short8v af1 = *(const short8v*)(hs + arow * 1024 +
                                  ((((kk + 1) * 64) + ag16) ^ swz_r));
                a0 = __builtin_amdgcn_mfma_f32_16x16x32_bf16(af0, bw[kk], a0, 0, 0, 0);
                a1 = __builtin_amdgcn_mfma_f32_16x16x32_bf16(af1, bw[kk + 1], a1, 0, 0, 0);
            }
            if (lane < 32) {   // rows 0..7 valid: row=(lane>>4)*4+reg, col=lane&15
#pragma unroll
                for (int reg = 0; reg < 4; ++reg) {
                    gsh[wv][(lane >> 4) * 4 + reg][lane & 15] = a0[reg] + a1[reg];
                }
            }
        }
        __syncthreads();   // (2) gates in gsh, xw in xsh

        // ---- gate nonlinearity + state update (tid<128: b=tid>>4, jj=tid&15) ----
        unsigned short hb16 = 0;
        int b_glob = 0;
        if (tid < 128) {
            const int bl = tid >> 4, jj = tid & 15;
            const unsigned short* xp = (const unsigned short*)xsh;
            const int vb = bl * 64 + jj;
            float gi = gsh[0][bl][jj] + bf2f(xp[vb]);
            float gf = gsh[1][bl][jj] + bf2f(xp[vb + 16]);
            float gg = gsh[2][bl][jj] + bf2f(xp[vb + 32]);
            float go = gsh[3][bl][jj] + bf2f(xp[vb + 48]);
            float si = fast_sigmoid(gi);
            float sf = fast_sigmoid(gf);
            float so = fast_sigmoid(go);
            c_st = sf * c_st + si * fast_tanh(gg);
            float hv = so * fast_tanh(c_st);
            hb16 = f2bf(hv);
            b_glob = bg * 8 + bl;
            // pack (jj even|odd) into one uint; even thread stores agent-atomic
            unsigned hv32 = hb16;
            unsigned other = (unsigned)__shfl_xor((int)hv32, 1);
            if (!(tid & 1)) {
                const int dp_w = dir * 2 + ((t + 1) & 1);
                __hip_atomic_store(
                    &h_pp[((size_t)dp_w * BB + b_glob) * 256 + jb * 8 + (jj >> 1)],
                    hv32 | (other << 16),
                    __ATOMIC_RELAXED, __HIP_MEMORY_SCOPE_AGENT);
            }
        }
        __syncthreads();   // (3) all h stores drained (vmcnt0 before barrier)

        if (t != TT - 1) {
            if (tid == 0) {
                __hip_atomic_store(&myflags[jb * 32], t + 1,
                                   __ATOMIC_RELEASE, __HIP_MEMORY_SCOPE_AGENT);
            }
            // deferred outcat write (not on the sync critical path)
            if (tid < 128) {
                outcat[((size_t)b_glob * TT + tt) * 1024 + dir * HH + js + (tid & 15)] = hb16;
            }
            // wave0: poll all 32 flags in parallel (relaxed agent loads, sc1-fresh)
            if (tid < 64) {
                const int l = tid & 31;
                const int target = t + 1;
                while (__hip_atomic_load(&myflags[l * 32], __ATOMIC_RELAXED,
                                         __HIP_MEMORY_SCOPE_AGENT) < target) {
                    __builtin_amdgcn_s_sleep(1);
                }
            }
            __syncthreads();   // (4) step barrier
        } else {
            if (tid < 128) {
                outcat[((size_t)b_glob * TT + tt) * 1024 + dir * HH + js + (tid & 15)] = hb16;
            }
        }
    }
}

// ---------------------------------------------------------------------------
// 4) Classifier + log_softmax, transposed write (B,C,T).
__global__ __launch_bounds__(256)
void classifier_k(const unsigned short* __restrict__ hcat, const float* __restrict__ truth,
                  const int* __restrict__ tf, const float* __restrict__ Wc,
                  const float* __restrict__ bc, float* __restrict__ out) {
    __shared__ float feat[8][1024];
    __shared__ float featp[8];
    const int tid = threadIdx.x;
    const int bt0 = blockIdx.x * 8;
    for (int i = tid; i < 8 * 128; i += 256) {   // 8 rows x 128 chunks(8 vals)
        int bl = i >> 7, ch = i & 127;
        uint4 u = *(const uint4*)(hcat + (size_t)(bt0 + bl) * 1024 + ch * 8);
        *(float4*)&feat[bl][ch * 8] = make_float4(bf_lo(u.x), bf_hi(u.x), bf_lo(u.y), bf_hi(u.y));
        *(float4*)&feat[bl][ch * 8 + 4] = make_float4(bf_lo(u.z), bf_hi(u.z), bf_lo(u.w), bf_hi(u.w));
    }
    if (tid < 8) {
        int bt = bt0 + tid;
        int t = bt & 511;
        featp[tid] = (t > 0 && tf[0] != 0) ? truth[bt - 1] : 0.f;
    }
    __syncthreads();
    const int bl = tid >> 5, c = tid & 31;
    const int bt = bt0 + bl;
    float acc = featp[bl] * Wc[c * 1025] + bc[c];
    const float* w = Wc + c * 1025 + 1;
    for (int f4 = 0; f4 < 256; ++f4) {
        const float4 fv = *(const float4*)&feat[bl][f4 * 4];
        acc = fmaf(fv.x, w[f4 * 4 + 0],
              fmaf(fv.y, w[f4 * 4 + 1],
              fmaf(fv.z, w[f4 * 4 + 2],
              fmaf(fv.w, w[f4 * 4 + 3], acc))));
    }
    float m = acc;
#pragma unroll
    for (int mk = 16; mk; mk >>= 1) m = fmaxf(m, __shfl_xor(m, mk));
    float e = expf(acc - m);
    float s = e;
#pragma unroll
    for (int mk = 16; mk; mk >>= 1) s += __shfl_xor(s, mk);
    float lse = m + logf(s);
    int b = bt >> 9, t = bt & 511;
    out[((size_t)b * CC + c) * TT + t] = acc - lse;
}

// ---------------------------------------------------------------------------
extern "C" void kernel_launch(void* const* d_in, const int* in_sizes, int n_in,
                              void* d_out, int out_size, void* d_ws, size_t ws_size,
                              hipStream_t stream) {
    const int* x = (const int*)d_in[0];
    const float* truth = (const float*)d_in[1];
    const int* tf = (const int*)d_in[2];
    const float* emb = (const float*)d_in[3];
    const float* Wih0f = (const float*)d_in[4];
    const float* Whh0f = (const float*)d_in[5];
    const float* bih0f = (const float*)d_in[6];
    const float* bhh0f = (const float*)d_in[7];
    const float* Wih0b = (const float*)d_in[8];
    const float* Whh0b = (const float*)d_in[9];
    const float* bih0b = (const float*)d_in[10];
    const float* bhh0b = (const float*)d_in[11];
    const float* Wih1f = (const float*)d_in[12];
    const float* Whh1f = (const float*)d_in[13];
    const float* bih1f = (const float*)d_in[14];
    const float* bhh1f = (const float*)d_in[15];
    const float* Wih1b = (const float*)d_in[16];
    const float* Whh1b = (const float*)d_in[17];
    const float* bih1b = (const float*)d_in[18];
    const float* bhh1b = (const float*)d_in[19];
    const float* Wc = (const float*)d_in[20];
    const float* bc = (const float*)d_in[21];
    float* out = (float*)d_out;

    // ws layout (bytes)
    const size_t off_h0  = 0;                       // (B,T,512) bf16 : 16 MB
    const size_t off_xwf = 16777216;                // perm (32,512,32,64) bf16: 64 MB
    const size_t off_xwb = off_xwf + 67108864;
    const size_t off_hc1 = off_xwb + 67108864;      // (B,T,1024) bf16: 32 MB
    const size_t off_hc2 = off_hc1 + 33554432;
    const size_t off_hpp = off_hc2 + 33554432;      // uint h state: 256 KB
    const size_t off_cnt = off_hpp + 262144;        // flags 8*32*128B = 32 KB
    const size_t need = off_cnt + 32768;
    if (ws_size < need) return;

    char* ws = (char*)d_ws;
    unsigned short* h0  = (unsigned short*)(ws + off_h0);
    unsigned short* xwf = (unsigned short*)(ws + off_xwf);
    unsigned short* xwb = (unsigned short*)(ws + off_xwb);
    unsigned short* hc1 = (unsigned short*)(ws + off_hc1);
    unsigned short* hc2 = (unsigned short*)(ws + off_hc2);
    unsigned int*   hpp = (unsigned int*)(ws + off_hpp);
    int* cnt = (int*)(ws + off_cnt);

    embed_k<<<8192, 256, 0, stream>>>(x, emb, h0);

    // layer 0
    gemm_xw<<<8192, 256, 0, stream>>>(h0, Wih0f, bih0f, bhh0f, xwf, BB * TT, EE);
    gemm_xw<<<8192, 256, 0, stream>>>(h0, Wih0b, bih0b, bhh0b, xwb, BB * TT, EE);
    (void)hipMemsetAsync(ws + off_hpp, 0, 262144 + 32768, stream);
    lstm_scan<<<256, 256, 0, stream>>>(Whh0f, Whh0b, xwf, xwb, hc1, hpp, cnt);

    // layer 1
    gemm_xw<<<8192, 256, 0, stream>>>(hc1, Wih1f, bih1f, bhh1f, xwf, BB * TT, 1024);
    gemm_xw<<<8192, 256, 0, stream>>>(hc1, Wih1b, bih1b, bhh1b, xwb, BB * TT, 1024);
    (void)hipMemsetAsync(ws + off_hpp, 0, 262144 + 32768, stream);
    lstm_scan<<<256, 256, 0, stream>>>(Whh1f, Whh1b, xwf, xwb, hc2, hpp, cnt);

    classifier_k<<<2048, 256, 0, stream>>>(hc2, truth, tf, Wc, bc, out);
}

// Round 6
// 6463.231 us; speedup vs baseline: 2.9908x; 1.1354x over previous
//
#include <hip/hip_runtime.h>

// ---------------------------------------------------------------------------
// LSTM_NER_TeacherForcing: B=32, T=512, E=512, H=512, V=50000, C=32, L=2
// embed -> [mfma gemm xw -> persistent scan] x2 -> classifier
// Round 6 (scan only):
//   - h stage loads COALESCED: thread(row,k) loads uints {k+32j} -> each
//     instruction 128B contiguous per 32-lane group (was 32B-strided);
//   - LDS staging as 8x b32 writes, bank = k ^ perm(row): conflict-free
//     (was 8-way-conflicted uint4 writes -> 4.6e7 SQ_LDS_BANK_CONFLICT);
//   - barrier: all 4 waves poll the 32 flags themselves; stage-sync doubles
//     as post-poll rendezvous -> 3 syncthreads/step instead of 4.
// ---------------------------------------------------------------------------

#define BB 32
#define TT 512
#define EE 512
#define HH 512
#define NG 2048   // 4*H gate rows
#define CC 32

typedef __attribute__((ext_vector_type(8))) short short8v;
typedef __attribute__((ext_vector_type(4))) float float4v;

__device__ __forceinline__ float bf2f(unsigned short u) {
    return __uint_as_float(((unsigned)u) << 16);
}
__device__ __forceinline__ float bf_lo(unsigned u) { return __uint_as_float(u << 16); }
__device__ __forceinline__ float bf_hi(unsigned u) { return __uint_as_float(u & 0xffff0000u); }
__device__ __forceinline__ unsigned short f2bf(float f) {
    unsigned u = __float_as_uint(f);
    u += 0x7fffu + ((u >> 16) & 1u);   // RNE
    return (unsigned short)(u >> 16);
}
__device__ __forceinline__ float fast_sigmoid(float x) {
    return 1.f / (1.f + __expf(-x));
}
__device__ __forceinline__ float fast_tanh(float x) {
    x = fminf(fmaxf(x, -15.f), 15.f);
    float e = __expf(2.f * x);
    return (e - 1.f) / (e + 1.f);
}

// ---------------------------------------------------------------------------
// 1) Embedding gather: h0[b,t,e] = emb[x[b,t]][e]  (f32 -> bf16)
__global__ __launch_bounds__(256)
void embed_k(const int* __restrict__ x, const float* __restrict__ emb,
             unsigned short* __restrict__ h0) {
    int idx = blockIdx.x * 256 + threadIdx.x;    // one float4 each
    int row = idx >> 7;                          // E/4 = 128 chunks per row
    int c4  = idx & 127;
    int tok = x[row];
    float4 v = *(const float4*)(emb + ((size_t)tok << 9) + (c4 << 2));
    ushort4 o;
    o.x = f2bf(v.x); o.y = f2bf(v.y); o.z = f2bf(v.z); o.w = f2bf(v.w);
    *(ushort4*)(h0 + ((size_t)row << 9) + (c4 << 2)) = o;
}

// ---------------------------------------------------------------------------
// 2) Input GEMM via MFMA, output written PERMUTED for the scan:
// xwp[((jb*512 + t)*32 + b)*64 + gate*16 + jj], jb=(n&511)>>4, gate=n>>9, jj=n&15
__global__ __launch_bounds__(256)
void gemm_xw(const unsigned short* __restrict__ A, const float* __restrict__ Bw,
             const float* __restrict__ bih, const float* __restrict__ bhh,
             unsigned short* __restrict__ Cp, int M, int K) {
    __shared__ unsigned short As[64][40];   // row-major (m,k), pad to 40
    __shared__ unsigned short Bs[64][40];   // (n,k)
    const int bn = blockIdx.x & 31, bm = blockIdx.x >> 5;
    const int tid = threadIdx.x;
    const int wv = tid >> 6, lane = tid & 63;
    const int wm = (wv >> 1) * 32, wn = (wv & 1) * 32;
    const int sr = tid >> 2, sk = (tid & 3) * 8;   // staging: row, k-chunk of 8
    const int fr = lane & 15, fk = (lane >> 4) * 8;

    float4v acc[2][2];
#pragma unroll
    for (int i = 0; i < 2; ++i)
#pragma unroll
        for (int j = 0; j < 2; ++j) acc[i][j] = (float4v)(0.0f);

    for (int k0 = 0; k0 < K; k0 += 32) {
        *(uint4*)&As[sr][sk] = *(const uint4*)(A + (size_t)(bm * 64 + sr) * K + k0 + sk);
        const float* bp = Bw + (size_t)(bn * 64 + sr) * K + k0 + sk;
        const float4 b0 = *(const float4*)bp;
        const float4 b1 = *(const float4*)(bp + 4);
        ushort4 o0 = {f2bf(b0.x), f2bf(b0.y), f2bf(b0.z), f2bf(b0.w)};
        ushort4 o1 = {f2bf(b1.x), f2bf(b1.y), f2bf(b1.z), f2bf(b1.w)};
        *(ushort4*)&Bs[sr][sk] = o0;
        *(ushort4*)&Bs[sr][sk + 4] = o1;
        __syncthreads();

        short8v a0 = *(const short8v*)&As[wm + fr][fk];
        short8v a1 = *(const short8v*)&As[wm + 16 + fr][fk];
        short8v bb0 = *(const short8v*)&Bs[wn + fr][fk];
        short8v bb1 = *(const short8v*)&Bs[wn + 16 + fr][fk];
        acc[0][0] = __builtin_amdgcn_mfma_f32_16x16x32_bf16(a0, bb0, acc[0][0], 0, 0, 0);
        acc[0][1] = __builtin_amdgcn_mfma_f32_16x16x32_bf16(a0, bb1, acc[0][1], 0, 0, 0);
        acc[1][0] = __builtin_amdgcn_mfma_f32_16x16x32_bf16(a1, bb0, acc[1][0], 0, 0, 0);
        acc[1][1] = __builtin_amdgcn_mfma_f32_16x16x32_bf16(a1, bb1, acc[1][1], 0, 0, 0);
        __syncthreads();
    }

    const int r4 = (lane >> 4) * 4;
#pragma unroll
    for (int nt = 0; nt < 2; ++nt) {
        const int nglob = bn * 64 + wn + nt * 16 + fr;
        const float bias = bih[nglob] + bhh[nglob];
        const int gate = nglob >> 9;
        const int jbv = (nglob & 511) >> 4;
        const int loc = gate * 16 + (nglob & 15);
#pragma unroll
        for (int mt = 0; mt < 2; ++mt) {
#pragma unroll
            for (int i = 0; i < 4; ++i) {
                const int mglob = bm * 64 + wm + mt * 16 + r4 + i;
                const int b = mglob >> 9, t = mglob & 511;
                Cp[(((size_t)jbv * 512 + t) * 32 + b) * 64 + loc] =
                    f2bf(acc[mt][nt][i] + bias);
            }
        }
    }
}

// ---------------------------------------------------------------------------
// 3) Persistent bidirectional LSTM scan. grid = 256 blocks, 256 thr (4 waves).
// blk: grp = blk&7 (dir*4+bg, same-XCD heuristic), jb = blk>>3 (16 h-cols).
// Wave w = gate type w: Whh rows in VGPRs (16 B-frags). h crosses blocks as
// packed uint (2xbf16) agent-scope atomics; flags per block, release/relaxed.
__global__ __launch_bounds__(256, 1)
void lstm_scan(const float* __restrict__ WhhF, const float* __restrict__ WhhB,
               const unsigned short* __restrict__ xwF, const unsigned short* __restrict__ xwB,
               unsigned short* __restrict__ outcat,   // (B,T,1024) bf16
               unsigned int* __restrict__ h_pp,       // [dir*2+par][32][256] uint
               int* __restrict__ cnt) {               // flags: 8 grp x 32 blk x 128B
    __shared__ __align__(16) unsigned char hs[16384];  // bf16 [16 rows][512 k], swizzled
    __shared__ float gsh[4][8][16];
    __shared__ unsigned xsh[256];

    const int blk = blockIdx.x;
    const int grp = blk & 7, jb = blk >> 3;
    const int bg = grp & 3, dir = grp >> 2;
    const int tid = threadIdx.x;
    const int wv = tid >> 6, lane = tid & 63;
    const float* Whh = dir ? WhhB : WhhF;
    const unsigned short* xw = dir ? xwB : xwF;
    const int js = jb << 4;
    int* const myflags = cnt + grp * 32 * 32;   // flag j at myflags[j*32]

    // ---- preload weights into registers: wave wv = gate type wv ----
    short8v bw[16];
    {
        const float* wrow = Whh + (size_t)(wv * 512 + js + (lane & 15)) * HH
                            + (lane >> 4) * 8;
#pragma unroll
        for (int kk = 0; kk < 16; ++kk) {
            const float4 f0 = *(const float4*)(wrow + kk * 32);
            const float4 f1 = *(const float4*)(wrow + kk * 32 + 4);
            short8v b;
            b[0] = (short)f2bf(f0.x); b[1] = (short)f2bf(f0.y);
            b[2] = (short)f2bf(f0.z); b[3] = (short)f2bf(f0.w);
            b[4] = (short)f2bf(f1.x); b[5] = (short)f2bf(f1.y);
            b[6] = (short)f2bf(f1.z); b[7] = (short)f2bf(f1.w);
            bw[kk] = b;
        }
    }

    // zero hs rows 8..15 once (A-frag rows 8-15 are never re-written)
    for (int i = tid; i < 8 * 64; i += 256) {
        int r = 8 + (i >> 6), c = i & 63;
        *(uint4*)(hs + r * 1024 + ((c * 16) ^ ((r & 7) << 4))) = make_uint4(0, 0, 0, 0);
    }

    float c_st = 0.f;
    // stage coords: thread -> row tid>>5 (0..7), k-lane tid&31
    const int srow = tid >> 5, kcol = tid & 31;
    const unsigned swz_w = (srow & 7) << 4;
    // A-frag read coords
    const int arow = lane & 15, ag16 = (lane >> 4) * 16;
    const unsigned swz_r = (arow & 7) << 4;
    __syncthreads();

    for (int t = 0; t < TT; ++t) {
        const int tt = dir ? (TT - 1 - t) : t;
        const int dp_r = dir * 2 + (t & 1);

        // ---- distributed poll: every wave checks all 32 flags (lanes 0-31) ----
        if (t > 0) {
            const int l = lane & 31;
            while (__hip_atomic_load(&myflags[l * 32], __ATOMIC_RELAXED,
                                     __HIP_MEMORY_SCOPE_AGENT) < t) {
                __builtin_amdgcn_s_sleep(1);
            }
        }

        // xw slice for this step (1KB contiguous): one uint per thread
        const unsigned xv = *(const unsigned*)(
            xw + (((size_t)jb * 512 + tt) * 32 + bg * 8) * 64 + 2 * tid);

        // ---- stage h: COALESCED agent-atomic loads (instr j = 128B/32 lanes) ----
        {
            const unsigned int* hsrc =
                h_pp + ((size_t)dp_r * BB + bg * 8 + srow) * 256;
            unsigned u0 = __hip_atomic_load(hsrc + kcol,       __ATOMIC_RELAXED, __HIP_MEMORY_SCOPE_AGENT);
            unsigned u1 = __hip_atomic_load(hsrc + kcol + 32,  __ATOMIC_RELAXED, __HIP_MEMORY_SCOPE_AGENT);
            unsigned u2 = __hip_atomic_load(hsrc + kcol + 64,  __ATOMIC_RELAXED, __HIP_MEMORY_SCOPE_AGENT);
            unsigned u3 = __hip_atomic_load(hsrc + kcol + 96,  __ATOMIC_RELAXED, __HIP_MEMORY_SCOPE_AGENT);
            unsigned u4 = __hip_atomic_load(hsrc + kcol + 128, __ATOMIC_RELAXED, __HIP_MEMORY_SCOPE_AGENT);
            unsigned u5 = __hip_atomic_load(hsrc + kcol + 160, __ATOMIC_RELAXED, __HIP_MEMORY_SCOPE_AGENT);
            unsigned u6 = __hip_atomic_load(hsrc + kcol + 192, __ATOMIC_RELAXED, __HIP_MEMORY_SCOPE_AGENT);
            unsigned u7 = __hip_atomic_load(hsrc + kcol + 224, __ATOMIC_RELAXED, __HIP_MEMORY_SCOPE_AGENT);
            xsh[tid] = xv;
            // uint j holds cols 2*(kcol+32j), +1 -> pre-swizzle byte 4*kcol+128*j.
            // b32 writes: bank = kcol ^ perm(srow) -> conflict-free.
            unsigned char* hrow = hs + srow * 1024;
            *(unsigned*)(hrow + ((4 * kcol +   0) ^ swz_w)) = u0;
            *(unsigned*)(hrow + ((4 * kcol + 128) ^ swz_w)) = u1;
            *(unsigned*)(hrow + ((4 * kcol + 256) ^ swz_w)) = u2;
            *(unsigned*)(hrow + ((4 * kcol + 384) ^ swz_w)) = u3;
            *(unsigned*)(hrow + ((4 * kcol + 512) ^ swz_w)) = u4;
            *(unsigned*)(hrow + ((4 * kcol + 640) ^ swz_w)) = u5;
            *(unsigned*)(hrow + ((4 * kcol + 768) ^ swz_w)) = u6;
            *(unsigned*)(hrow + ((4 * kcol + 896) ^ swz_w)) = u7;
        }
        __syncthreads();   // (1) post-poll rendezvous + h staged

        // ---- MFMA: wave wv computes gates[wv][b 0..7][jj 0..15] over K=512 ----
        {
            float4v a0 = (float4v)(0.0f), a1 = (float4v)(0.0f);
#pragma unroll
            for (int kk = 0; kk < 16; kk += 2) {
                short8v af0 = *(const short8v*)(hs + arow * 1024 +
                                  (((kk * 64) + ag16) ^ swz_r));
                short8v af1 = *(const short8v*)(hs + arow * 1024 +
                                  ((((kk + 1) * 64) + ag16) ^ swz_r));
                a0 = __builtin_amdgcn_mfma_f32_16x16x32_bf16(af0, bw[kk], a0, 0, 0, 0);
                a1 = __builtin_amdgcn_mfma_f32_16x16x32_bf16(af1, bw[kk + 1], a1, 0, 0, 0);
            }
            if (lane < 32) {   // rows 0..7 valid: row=(lane>>4)*4+reg, col=lane&15
#pragma unroll
                for (int reg = 0; reg < 4; ++reg) {
                    gsh[wv][(lane >> 4) * 4 + reg][lane & 15] = a0[reg] + a1[reg];
                }
            }
        }
        __syncthreads();   // (2) gates in gsh, xw in xsh

        // ---- gate nonlinearity + state update (tid<128: b=tid>>4, jj=tid&15) ----
        unsigned short hb16 = 0;
        int b_glob = 0;
        if (tid < 128) {
            const int bl = tid >> 4, jj = tid & 15;
            const unsigned short* xp = (const unsigned short*)xsh;
            const int vb = bl * 64 + jj;
            float gi = gsh[0][bl][jj] + bf2f(xp[vb]);
            float gf = gsh[1][bl][jj] + bf2f(xp[vb + 16]);
            float gg = gsh[2][bl][jj] + bf2f(xp[vb + 32]);
            float go = gsh[3][bl][jj] + bf2f(xp[vb + 48]);
            float si = fast_sigmoid(gi);
            float sf = fast_sigmoid(gf);
            float so = fast_sigmoid(go);
            c_st = sf * c_st + si * fast_tanh(gg);
            float hv = so * fast_tanh(c_st);
            hb16 = f2bf(hv);
            b_glob = bg * 8 + bl;
            // pack (jj even|odd) into one uint; even thread stores agent-atomic
            unsigned hv32 = hb16;
            unsigned other = (unsigned)__shfl_xor((int)hv32, 1);
            if (!(tid & 1)) {
                const int dp_w = dir * 2 + ((t + 1) & 1);
                __hip_atomic_store(
                    &h_pp[((size_t)dp_w * BB + b_glob) * 256 + jb * 8 + (jj >> 1)],
                    hv32 | (other << 16),
                    __ATOMIC_RELAXED, __HIP_MEMORY_SCOPE_AGENT);
            }
        }
        __syncthreads();   // (3) all waves' h stores drained (vmcnt0 before barrier)

        // announce completion; outcat write off the critical path
        if (t != TT - 1 && tid == 0) {
            __hip_atomic_store(&myflags[jb * 32], t + 1,
                               __ATOMIC_RELEASE, __HIP_MEMORY_SCOPE_AGENT);
        }
        if (tid < 128) {
            outcat[((size_t)b_glob * TT + tt) * 1024 + dir * HH + js + (tid & 15)] = hb16;
        }
    }
}

// ---------------------------------------------------------------------------
// 4) Classifier + log_softmax, transposed write (B,C,T).
__global__ __launch_bounds__(256)
void classifier_k(const unsigned short* __restrict__ hcat, const float* __restrict__ truth,
                  const int* __restrict__ tf, const float* __restrict__ Wc,
                  const float* __restrict__ bc, float* __restrict__ out) {
    __shared__ float feat[8][1024];
    __shared__ float featp[8];
    const int tid = threadIdx.x;
    const int bt0 = blockIdx.x * 8;
    for (int i = tid; i < 8 * 128; i += 256) {   // 8 rows x 128 chunks(8 vals)
        int bl = i >> 7, ch = i & 127;
        uint4 u = *(const uint4*)(hcat + (size_t)(bt0 + bl) * 1024 + ch * 8);
        *(float4*)&feat[bl][ch * 8] = make_float4(bf_lo(u.x), bf_hi(u.x), bf_lo(u.y), bf_hi(u.y));
        *(float4*)&feat[bl][ch * 8 + 4] = make_float4(bf_lo(u.z), bf_hi(u.z), bf_lo(u.w), bf_hi(u.w));
    }
    if (tid < 8) {
        int bt = bt0 + tid;
        int t = bt & 511;
        featp[tid] = (t > 0 && tf[0] != 0) ? truth[bt - 1] : 0.f;
    }
    __syncthreads();
    const int bl = tid >> 5, c = tid & 31;
    const int bt = bt0 + bl;
    float acc = featp[bl] * Wc[c * 1025] + bc[c];
    const float* w = Wc + c * 1025 + 1;
    for (int f4 = 0; f4 < 256; ++f4) {
        const float4 fv = *(const float4*)&feat[bl][f4 * 4];
        acc = fmaf(fv.x, w[f4 * 4 + 0],
              fmaf(fv.y, w[f4 * 4 + 1],
              fmaf(fv.z, w[f4 * 4 + 2],
              fmaf(fv.w, w[f4 * 4 + 3], acc))));
    }
    float m = acc;
#pragma unroll
    for (int mk = 16; mk; mk >>= 1) m = fmaxf(m, __shfl_xor(m, mk));
    float e = expf(acc - m);
    float s = e;
#pragma unroll
    for (int mk = 16; mk; mk >>= 1) s += __shfl_xor(s, mk);
    float lse = m + logf(s);
    int b = bt >> 9, t = bt & 511;
    out[((size_t)b * CC + c) * TT + t] = acc - lse;
}

// ---------------------------------------------------------------------------
extern "C" void kernel_launch(void* const* d_in, const int* in_sizes, int n_in,
                              void* d_out, int out_size, void* d_ws, size_t ws_size,
                              hipStream_t stream) {
    const int* x = (const int*)d_in[0];
    const float* truth = (const float*)d_in[1];
    const int* tf = (const int*)d_in[2];
    const float* emb = (const float*)d_in[3];
    const float* Wih0f = (const float*)d_in[4];
    const float* Whh0f = (const float*)d_in[5];
    const float* bih0f = (const float*)d_in[6];
    const float* bhh0f = (const float*)d_in[7];
    const float* Wih0b = (const float*)d_in[8];
    const float* Whh0b = (const float*)d_in[9];
    const float* bih0b = (const float*)d_in[10];
    const float* bhh0b = (const float*)d_in[11];
    const float* Wih1f = (const float*)d_in[12];
    const float* Whh1f = (const float*)d_in[13];
    const float* bih1f = (const float*)d_in[14];
    const float* bhh1f = (const float*)d_in[15];
    const float* Wih1b = (const float*)d_in[16];
    const float* Whh1b = (const float*)d_in[17];
    const float* bih1b = (const float*)d_in[18];
    const float* bhh1b = (const float*)d_in[19];
    const float* Wc = (const float*)d_in[20];
    const float* bc = (const float*)d_in[21];
    float* out = (float*)d_out;

    // ws layout (bytes)
    const size_t off_h0  = 0;                       // (B,T,512) bf16 : 16 MB
    const size_t off_xwf = 16777216;                // perm (32,512,32,64) bf16: 64 MB
    const size_t off_xwb = off_xwf + 67108864;
    const size_t off_hc1 = off_xwb + 67108864;      // (B,T,1024) bf16: 32 MB
    const size_t off_hc2 = off_hc1 + 33554432;
    const size_t off_hpp = off_hc2 + 33554432;      // uint h state: 256 KB
    const size_t off_cnt = off_hpp + 262144;        // flags 8*32*128B = 32 KB
    const size_t need = off_cnt + 32768;
    if (ws_size < need) return;

    char* ws = (char*)d_ws;
    unsigned short* h0  = (unsigned short*)(ws + off_h0);
    unsigned short* xwf = (unsigned short*)(ws + off_xwf);
    unsigned short* xwb = (unsigned short*)(ws + off_xwb);
    unsigned short* hc1 = (unsigned short*)(ws + off_hc1);
    unsigned short* hc2 = (unsigned short*)(ws + off_hc2);
    unsigned int*   hpp = (unsigned int*)(ws + off_hpp);
    int* cnt = (int*)(ws + off_cnt);

    embed_k<<<8192, 256, 0, stream>>>(x, emb, h0);

    // layer 0
    gemm_xw<<<8192, 256, 0, stream>>>(h0, Wih0f, bih0f, bhh0f, xwf, BB * TT, EE);
    gemm_xw<<<8192, 256, 0, stream>>>(h0, Wih0b, bih0b, bhh0b, xwb, BB * TT, EE);
    (void)hipMemsetAsync(ws + off_hpp, 0, 262144 + 32768, stream);
    lstm_scan<<<256, 256, 0, stream>>>(Whh0f, Whh0b, xwf, xwb, hc1, hpp, cnt);

    // layer 1
    gemm_xw<<<8192, 256, 0, stream>>>(hc1, Wih1f, bih1f, bhh1f, xwf, BB * TT, 1024);
    gemm_xw<<<8192, 256, 0, stream>>>(hc1, Wih1b, bih1b, bhh1b, xwb, BB * TT, 1024);
    (void)hipMemsetAsync(ws + off_hpp, 0, 262144 + 32768, stream);
    lstm_scan<<<256, 256, 0, stream>>>(Whh1f, Whh1b, xwf, xwb, hc2, hpp, cnt);

    classifier_k<<<2048, 256, 0, stream>>>(hc2, truth, tf, Wc, bc, out);
}

// Round 7
// 3176.650 us; speedup vs baseline: 6.0852x; 2.0346x over previous
//
#include <hip/hip_runtime.h>

// ---------------------------------------------------------------------------
// LSTM_NER_TeacherForcing: B=32, T=512, E=512, H=512, V=50000, C=32, L=2
// embed -> [mfma gemm xw -> persistent scan] x2 -> classifier
// Round 7 (scan sync rewrite):
//   - h crosses blocks as SELF-VALIDATING 64-bit packets {seq | 2xbf16} via
//     relaxed agent atomics; consumers poll the data itself (seq==t). No
//     flags, no release fences, no store-drain leg: 4 coherence legs -> 2.
//   - 4-slot rotation (slot=t&3) provides overwrite safety (skew<=1 step,
//     reuse distance 4). memset(0) == initial state (seq=0, h=0).
//   - xw load hoisted above the poll; xsh double-buffered -> 2 barriers/step.
// ---------------------------------------------------------------------------

#define BB 32
#define TT 512
#define EE 512
#define HH 512
#define NG 2048   // 4*H gate rows
#define CC 32

typedef __attribute__((ext_vector_type(8))) short short8v;
typedef __attribute__((ext_vector_type(4))) float float4v;
typedef unsigned long long u64;

__device__ __forceinline__ float bf2f(unsigned short u) {
    return __uint_as_float(((unsigned)u) << 16);
}
__device__ __forceinline__ float bf_lo(unsigned u) { return __uint_as_float(u << 16); }
__device__ __forceinline__ float bf_hi(unsigned u) { return __uint_as_float(u & 0xffff0000u); }
__device__ __forceinline__ unsigned short f2bf(float f) {
    unsigned u = __float_as_uint(f);
    u += 0x7fffu + ((u >> 16) & 1u);   // RNE
    return (unsigned short)(u >> 16);
}
__device__ __forceinline__ float fast_sigmoid(float x) {
    return 1.f / (1.f + __expf(-x));
}
__device__ __forceinline__ float fast_tanh(float x) {
    x = fminf(fmaxf(x, -15.f), 15.f);
    float e = __expf(2.f * x);
    return (e - 1.f) / (e + 1.f);
}

// ---------------------------------------------------------------------------
// 1) Embedding gather: h0[b,t,e] = emb[x[b,t]][e]  (f32 -> bf16)
__global__ __launch_bounds__(256)
void embed_k(const int* __restrict__ x, const float* __restrict__ emb,
             unsigned short* __restrict__ h0) {
    int idx = blockIdx.x * 256 + threadIdx.x;    // one float4 each
    int row = idx >> 7;                          // E/4 = 128 chunks per row
    int c4  = idx & 127;
    int tok = x[row];
    float4 v = *(const float4*)(emb + ((size_t)tok << 9) + (c4 << 2));
    ushort4 o;
    o.x = f2bf(v.x); o.y = f2bf(v.y); o.z = f2bf(v.z); o.w = f2bf(v.w);
    *(ushort4*)(h0 + ((size_t)row << 9) + (c4 << 2)) = o;
}

// ---------------------------------------------------------------------------
// 2) Input GEMM via MFMA, output written PERMUTED for the scan:
// xwp[((jb*512 + t)*32 + b)*64 + gate*16 + jj], jb=(n&511)>>4, gate=n>>9, jj=n&15
__global__ __launch_bounds__(256)
void gemm_xw(const unsigned short* __restrict__ A, const float* __restrict__ Bw,
             const float* __restrict__ bih, const float* __restrict__ bhh,
             unsigned short* __restrict__ Cp, int M, int K) {
    __shared__ unsigned short As[64][40];   // row-major (m,k), pad to 40
    __shared__ unsigned short Bs[64][40];   // (n,k)
    const int bn = blockIdx.x & 31, bm = blockIdx.x >> 5;
    const int tid = threadIdx.x;
    const int wv = tid >> 6, lane = tid & 63;
    const int wm = (wv >> 1) * 32, wn = (wv & 1) * 32;
    const int sr = tid >> 2, sk = (tid & 3) * 8;   // staging: row, k-chunk of 8
    const int fr = lane & 15, fk = (lane >> 4) * 8;

    float4v acc[2][2];
#pragma unroll
    for (int i = 0; i < 2; ++i)
#pragma unroll
        for (int j = 0; j < 2; ++j) acc[i][j] = (float4v)(0.0f);

    for (int k0 = 0; k0 < K; k0 += 32) {
        *(uint4*)&As[sr][sk] = *(const uint4*)(A + (size_t)(bm * 64 + sr) * K + k0 + sk);
        const float* bp = Bw + (size_t)(bn * 64 + sr) * K + k0 + sk;
        const float4 b0 = *(const float4*)bp;
        const float4 b1 = *(const float4*)(bp + 4);
        ushort4 o0 = {f2bf(b0.x), f2bf(b0.y), f2bf(b0.z), f2bf(b0.w)};
        ushort4 o1 = {f2bf(b1.x), f2bf(b1.y), f2bf(b1.z), f2bf(b1.w)};
        *(ushort4*)&Bs[sr][sk] = o0;
        *(ushort4*)&Bs[sr][sk + 4] = o1;
        __syncthreads();

        short8v a0 = *(const short8v*)&As[wm + fr][fk];
        short8v a1 = *(const short8v*)&As[wm + 16 + fr][fk];
        short8v bb0 = *(const short8v*)&Bs[wn + fr][fk];
        short8v bb1 = *(const short8v*)&Bs[wn + 16 + fr][fk];
        acc[0][0] = __builtin_amdgcn_mfma_f32_16x16x32_bf16(a0, bb0, acc[0][0], 0, 0, 0);
        acc[0][1] = __builtin_amdgcn_mfma_f32_16x16x32_bf16(a0, bb1, acc[0][1], 0, 0, 0);
        acc[1][0] = __builtin_amdgcn_mfma_f32_16x16x32_bf16(a1, bb0, acc[1][0], 0, 0, 0);
        acc[1][1] = __builtin_amdgcn_mfma_f32_16x16x32_bf16(a1, bb1, acc[1][1], 0, 0, 0);
        __syncthreads();
    }

    const int r4 = (lane >> 4) * 4;
#pragma unroll
    for (int nt = 0; nt < 2; ++nt) {
        const int nglob = bn * 64 + wn + nt * 16 + fr;
        const float bias = bih[nglob] + bhh[nglob];
        const int gate = nglob >> 9;
        const int jbv = (nglob & 511) >> 4;
        const int loc = gate * 16 + (nglob & 15);
#pragma unroll
        for (int mt = 0; mt < 2; ++mt) {
#pragma unroll
            for (int i = 0; i < 4; ++i) {
                const int mglob = bm * 64 + wm + mt * 16 + r4 + i;
                const int b = mglob >> 9, t = mglob & 511;
                Cp[(((size_t)jbv * 512 + t) * 32 + b) * 64 + loc] =
                    f2bf(acc[mt][nt][i] + bias);
            }
        }
    }
}

// ---------------------------------------------------------------------------
// 3) Persistent bidirectional LSTM scan. grid = 256 blocks, 256 thr (4 waves).
// blk: grp = blk&7 (dir*4+bg, same-XCD heuristic), jb = blk>>3 (16 h-cols).
// Wave w = gate type w (Whh rows in VGPRs). h crosses blocks as 64-bit
// {seq|2xbf16} packets, relaxed agent atomics, 4-slot rotation, data-polled.
__global__ __launch_bounds__(256, 1)
void lstm_scan(const float* __restrict__ WhhF, const float* __restrict__ WhhB,
               const unsigned short* __restrict__ xwF, const unsigned short* __restrict__ xwB,
               unsigned short* __restrict__ outcat,   // (B,T,1024) bf16
               u64* __restrict__ h_pp) {              // [(slot*2+dir)*32+b][256] u64
    __shared__ __align__(16) unsigned char hs[16384];  // bf16 [16 rows][512 k], swizzled
    __shared__ float gsh[4][8][16];
    __shared__ unsigned xsh[2][256];

    const int blk = blockIdx.x;
    const int grp = blk & 7, jb = blk >> 3;
    const int bg = grp & 3, dir = grp >> 2;
    const int tid = threadIdx.x;
    const int wv = tid >> 6, lane = tid & 63;
    const float* Whh = dir ? WhhB : WhhF;
    const unsigned short* xw = dir ? xwB : xwF;
    const int js = jb << 4;

    // ---- preload weights into registers: wave wv = gate type wv ----
    short8v bw[16];
    {
        const float* wrow = Whh + (size_t)(wv * 512 + js + (lane & 15)) * HH
                            + (lane >> 4) * 8;
#pragma unroll
        for (int kk = 0; kk < 16; ++kk) {
            const float4 f0 = *(const float4*)(wrow + kk * 32);
            const float4 f1 = *(const float4*)(wrow + kk * 32 + 4);
            short8v b;
            b[0] = (short)f2bf(f0.x); b[1] = (short)f2bf(f0.y);
            b[2] = (short)f2bf(f0.z); b[3] = (short)f2bf(f0.w);
            b[4] = (short)f2bf(f1.x); b[5] = (short)f2bf(f1.y);
            b[6] = (short)f2bf(f1.z); b[7] = (short)f2bf(f1.w);
            bw[kk] = b;
        }
    }

    // zero hs rows 8..15 once (A-frag rows 8-15 are never re-written)
    for (int i = tid; i < 8 * 64; i += 256) {
        int r = 8 + (i >> 6), c = i & 63;
        *(uint4*)(hs + r * 1024 + ((c * 16) ^ ((r & 7) << 4))) = make_uint4(0, 0, 0, 0);
    }

    float c_st = 0.f;
    // stage coords: thread -> row tid>>5 (0..7), k-lane tid&31
    const int srow = tid >> 5, kcol = tid & 31;
    const unsigned swz_w = (srow & 7) << 4;
    // A-frag read coords
    const int arow = lane & 15, ag16 = (lane >> 4) * 16;
    const unsigned swz_r = (arow & 7) << 4;
    __syncthreads();

    for (int t = 0; t < TT; ++t) {
        const int tt = dir ? (TT - 1 - t) : t;

        // xw slice for this step (1KB contiguous), hoisted above the poll:
        // its HBM/L3 latency hides under the packet spin.
        const unsigned xv = *(const unsigned*)(
            xw + (((size_t)jb * 512 + tt) * 32 + bg * 8) * 64 + 2 * tid);

        // ---- stage h: poll self-validating packets until seq==t ----
        {
            const u64* hsrc =
                h_pp + ((size_t)((t & 3) * 2 + dir) * BB + bg * 8 + srow) * 256;
            const unsigned sq = (unsigned)t;
            u64 v0, v1, v2, v3, v4, v5, v6, v7;
            for (;;) {
                v0 = __hip_atomic_load(hsrc + kcol,       __ATOMIC_RELAXED, __HIP_MEMORY_SCOPE_AGENT);
                v1 = __hip_atomic_load(hsrc + kcol + 32,  __ATOMIC_RELAXED, __HIP_MEMORY_SCOPE_AGENT);
                v2 = __hip_atomic_load(hsrc + kcol + 64,  __ATOMIC_RELAXED, __HIP_MEMORY_SCOPE_AGENT);
                v3 = __hip_atomic_load(hsrc + kcol + 96,  __ATOMIC_RELAXED, __HIP_MEMORY_SCOPE_AGENT);
                v4 = __hip_atomic_load(hsrc + kcol + 128, __ATOMIC_RELAXED, __HIP_MEMORY_SCOPE_AGENT);
                v5 = __hip_atomic_load(hsrc + kcol + 160, __ATOMIC_RELAXED, __HIP_MEMORY_SCOPE_AGENT);
                v6 = __hip_atomic_load(hsrc + kcol + 192, __ATOMIC_RELAXED, __HIP_MEMORY_SCOPE_AGENT);
                v7 = __hip_atomic_load(hsrc + kcol + 224, __ATOMIC_RELAXED, __HIP_MEMORY_SCOPE_AGENT);
                unsigned ok = ((unsigned)(v0 >> 32) == sq) & ((unsigned)(v1 >> 32) == sq)
                            & ((unsigned)(v2 >> 32) == sq) & ((unsigned)(v3 >> 32) == sq)
                            & ((unsigned)(v4 >> 32) == sq) & ((unsigned)(v5 >> 32) == sq)
                            & ((unsigned)(v6 >> 32) == sq) & ((unsigned)(v7 >> 32) == sq);
                if (ok) break;
                __builtin_amdgcn_s_sleep(1);
            }
            xsh[t & 1][tid] = xv;
            unsigned char* hrow = hs + srow * 1024;
            *(unsigned*)(hrow + ((4 * kcol +   0) ^ swz_w)) = (unsigned)v0;
            *(unsigned*)(hrow + ((4 * kcol + 128) ^ swz_w)) = (unsigned)v1;
            *(unsigned*)(hrow + ((4 * kcol + 256) ^ swz_w)) = (unsigned)v2;
            *(unsigned*)(hrow + ((4 * kcol + 384) ^ swz_w)) = (unsigned)v3;
            *(unsigned*)(hrow + ((4 * kcol + 512) ^ swz_w)) = (unsigned)v4;
            *(unsigned*)(hrow + ((4 * kcol + 640) ^ swz_w)) = (unsigned)v5;
            *(unsigned*)(hrow + ((4 * kcol + 768) ^ swz_w)) = (unsigned)v6;
            *(unsigned*)(hrow + ((4 * kcol + 896) ^ swz_w)) = (unsigned)v7;
        }
        __syncthreads();   // (1) h staged + xsh written

        // ---- MFMA: wave wv computes gates[wv][b 0..7][jj 0..15] over K=512 ----
        {
            float4v a0 = (float4v)(0.0f), a1 = (float4v)(0.0f);
#pragma unroll
            for (int kk = 0; kk < 16; kk += 2) {
                short8v af0 = *(const short8v*)(hs + arow * 1024 +
                                  (((kk * 64) + ag16) ^ swz_r));
                short8v af1 = *(const short8v*)(hs + arow * 1024 +
                                  ((((kk + 1) * 64) + ag16) ^ swz_r));
                a0 = __builtin_amdgcn_mfma_f32_16x16x32_bf16(af0, bw[kk], a0, 0, 0, 0);
                a1 = __builtin_amdgcn_mfma_f32_16x16x32_bf16(af1, bw[kk + 1], a1, 0, 0, 0);
            }
            if (lane < 32) {   // rows 0..7 valid: row=(lane>>4)*4+reg, col=lane&15
#pragma unroll
                for (int reg = 0; reg < 4; ++reg) {
                    gsh[wv][(lane >> 4) * 4 + reg][lane & 15] = a0[reg] + a1[reg];
                }
            }
        }
        __syncthreads();   // (2) gates in gsh

        // ---- gate nonlinearity + state update (tid<128: b=tid>>4, jj=tid&15) ----
        if (tid < 128) {
            const int bl = tid >> 4, jj = tid & 15;
            const unsigned short* xp = (const unsigned short*)xsh[t & 1];
            const int vb = bl * 64 + jj;
            float gi = gsh[0][bl][jj] + bf2f(xp[vb]);
            float gf = gsh[1][bl][jj] + bf2f(xp[vb + 16]);
            float gg = gsh[2][bl][jj] + bf2f(xp[vb + 32]);
            float go = gsh[3][bl][jj] + bf2f(xp[vb + 48]);
            float si = fast_sigmoid(gi);
            float sf = fast_sigmoid(gf);
            float so = fast_sigmoid(go);
            c_st = sf * c_st + si * fast_tanh(gg);
            float hv = so * fast_tanh(c_st);
            const unsigned short hb16 = f2bf(hv);
            const int b_glob = bg * 8 + bl;
            // pack pair (jj even|odd) + seq into one 64-bit packet
            unsigned hv32 = hb16;
            unsigned other = (unsigned)__shfl_xor((int)hv32, 1);
            if (!(tid & 1)) {
                u64 pkt = ((u64)(unsigned)(t + 1) << 32) | (u64)(hv32 | (other << 16));
                __hip_atomic_store(
                    &h_pp[((size_t)(((t + 1) & 3) * 2 + dir) * BB + b_glob) * 256
                          + jb * 8 + (jj >> 1)],
                    pkt, __ATOMIC_RELAXED, __HIP_MEMORY_SCOPE_AGENT);
            }
            outcat[((size_t)b_glob * TT + tt) * 1024 + dir * HH + js + jj] = hb16;
        }
        // no third barrier: xsh is double-buffered; hs/gsh protected by (1),(2)
    }
}

// ---------------------------------------------------------------------------
// 4) Classifier + log_softmax, transposed write (B,C,T).
__global__ __launch_bounds__(256)
void classifier_k(const unsigned short* __restrict__ hcat, const float* __restrict__ truth,
                  const int* __restrict__ tf, const float* __restrict__ Wc,
                  const float* __restrict__ bc, float* __restrict__ out) {
    __shared__ float feat[8][1024];
    __shared__ float featp[8];
    const int tid = threadIdx.x;
    const int bt0 = blockIdx.x * 8;
    for (int i = tid; i < 8 * 128; i += 256) {   // 8 rows x 128 chunks(8 vals)
        int bl = i >> 7, ch = i & 127;
        uint4 u = *(const uint4*)(hcat + (size_t)(bt0 + bl) * 1024 + ch * 8);
        *(float4*)&feat[bl][ch * 8] = make_float4(bf_lo(u.x), bf_hi(u.x), bf_lo(u.y), bf_hi(u.y));
        *(float4*)&feat[bl][ch * 8 + 4] = make_float4(bf_lo(u.z), bf_hi(u.z), bf_lo(u.w), bf_hi(u.w));
    }
    if (tid < 8) {
        int bt = bt0 + tid;
        int t = bt & 511;
        featp[tid] = (t > 0 && tf[0] != 0) ? truth[bt - 1] : 0.f;
    }
    __syncthreads();
    const int bl = tid >> 5, c = tid & 31;
    const int bt = bt0 + bl;
    float acc = featp[bl] * Wc[c * 1025] + bc[c];
    const float* w = Wc + c * 1025 + 1;
    for (int f4 = 0; f4 < 256; ++f4) {
        const float4 fv = *(const float4*)&feat[bl][f4 * 4];
        acc = fmaf(fv.x, w[f4 * 4 + 0],
              fmaf(fv.y, w[f4 * 4 + 1],
              fmaf(fv.z, w[f4 * 4 + 2],
              fmaf(fv.w, w[f4 * 4 + 3], acc))));
    }
    float m = acc;
#pragma unroll
    for (int mk = 16; mk; mk >>= 1) m = fmaxf(m, __shfl_xor(m, mk));
    float e = expf(acc - m);
    float s = e;
#pragma unroll
    for (int mk = 16; mk; mk >>= 1) s += __shfl_xor(s, mk);
    float lse = m + logf(s);
    int b = bt >> 9, t = bt & 511;
    out[((size_t)b * CC + c) * TT + t] = acc - lse;
}

// ---------------------------------------------------------------------------
extern "C" void kernel_launch(void* const* d_in, const int* in_sizes, int n_in,
                              void* d_out, int out_size, void* d_ws, size_t ws_size,
                              hipStream_t stream) {
    const int* x = (const int*)d_in[0];
    const float* truth = (const float*)d_in[1];
    const int* tf = (const int*)d_in[2];
    const float* emb = (const float*)d_in[3];
    const float* Wih0f = (const float*)d_in[4];
    const float* Whh0f = (const float*)d_in[5];
    const float* bih0f = (const float*)d_in[6];
    const float* bhh0f = (const float*)d_in[7];
    const float* Wih0b = (const float*)d_in[8];
    const float* Whh0b = (const float*)d_in[9];
    const float* bih0b = (const float*)d_in[10];
    const float* bhh0b = (const float*)d_in[11];
    const float* Wih1f = (const float*)d_in[12];
    const float* Whh1f = (const float*)d_in[13];
    const float* bih1f = (const float*)d_in[14];
    const float* bhh1f = (const float*)d_in[15];
    const float* Wih1b = (const float*)d_in[16];
    const float* Whh1b = (const float*)d_in[17];
    const float* bih1b = (const float*)d_in[18];
    const float* bhh1b = (const float*)d_in[19];
    const float* Wc = (const float*)d_in[20];
    const float* bc = (const float*)d_in[21];
    float* out = (float*)d_out;

    // ws layout (bytes)
    const size_t off_h0  = 0;                       // (B,T,512) bf16 : 16 MB
    const size_t off_xwf = 16777216;                // perm (32,512,32,64) bf16: 64 MB
    const size_t off_xwb = off_xwf + 67108864;
    const size_t off_hc1 = off_xwb + 67108864;      // (B,T,1024) bf16: 32 MB
    const size_t off_hc2 = off_hc1 + 33554432;
    const size_t off_hpp = off_hc2 + 33554432;      // u64 packets: 4*2*32*256*8 = 512 KB
    const size_t need = off_hpp + 524288;
    if (ws_size < need) return;

    char* ws = (char*)d_ws;
    unsigned short* h0  = (unsigned short*)(ws + off_h0);
    unsigned short* xwf = (unsigned short*)(ws + off_xwf);
    unsigned short* xwb = (unsigned short*)(ws + off_xwb);
    unsigned short* hc1 = (unsigned short*)(ws + off_hc1);
    unsigned short* hc2 = (unsigned short*)(ws + off_hc2);
    u64*            hpp = (u64*)(ws + off_hpp);

    embed_k<<<8192, 256, 0, stream>>>(x, emb, h0);

    // layer 0
    gemm_xw<<<8192, 256, 0, stream>>>(h0, Wih0f, bih0f, bhh0f, xwf, BB * TT, EE);
    gemm_xw<<<8192, 256, 0, stream>>>(h0, Wih0b, bih0b, bhh0b, xwb, BB * TT, EE);
    (void)hipMemsetAsync(ws + off_hpp, 0, 524288, stream);
    lstm_scan<<<256, 256, 0, stream>>>(Whh0f, Whh0b, xwf, xwb, hc1, hpp);

    // layer 1
    gemm_xw<<<8192, 256, 0, stream>>>(hc1, Wih1f, bih1f, bhh1f, xwf, BB * TT, 1024);
    gemm_xw<<<8192, 256, 0, stream>>>(hc1, Wih1b, bih1b, bhh1b, xwb, BB * TT, 1024);
    (void)hipMemsetAsync(ws + off_hpp, 0, 524288, stream);
    lstm_scan<<<256, 256, 0, stream>>>(Whh1f, Whh1b, xwf, xwb, hc2, hpp);

    classifier_k<<<2048, 256, 0, stream>>>(hc2, truth, tf, Wc, bc, out);
}